// Round 18
// baseline (488.640 us; speedup 1.0000x reference)
//
#include <hip/hip_runtime.h>
#include <hip/hip_bf16.h>
#include <math.h>

typedef __bf16 bf16x8 __attribute__((ext_vector_type(8)));
typedef __bf16 bf16x4 __attribute__((ext_vector_type(4)));
typedef float  f32x4  __attribute__((ext_vector_type(4)));
typedef unsigned int u32x4 __attribute__((ext_vector_type(4)));
typedef __hip_bfloat16 bf16_t;

static constexpr int C_    = 128;
static constexpr int L_    = 56 * 56;        // tokens per image
static constexpr int M_    = 64 * L_;        // 200704 total tokens
static constexpr int NWIN  = 64 * 64;        // 4096 windows

// map windowed token index tw -> unwindowed token index (shift+window bijection)
__device__ inline long win_to_tok(int tw)
{
    int win = tw / 49, n = tw % 49;
    int bb  = win >> 6, wi = win & 63;
    int wh  = wi >> 3, wwp = wi & 7;
    int hs  = wh * 7 + n / 7;
    int wsv = wwp * 7 + n % 7;
    int hh  = (hs + 3) % 56;          // un-shift
    int ww  = (wsv + 3) % 56;
    return (long)bb * L_ + hh * 56 + ww;
}

__device__ inline unsigned int pk2(float lo, float hi)
{
    unsigned short a = __builtin_bit_cast(unsigned short, (__bf16)lo);
    unsigned short b = __builtin_bit_cast(unsigned short, (__bf16)hi);
    return (unsigned int)a | ((unsigned int)b << 16);
}

// tanh-form GELU: ~8 VALU ops, |err| <= ~3e-3 (threshold is 0.11).
__device__ inline float gelu_f(float x)
{
    float u = 0.7978845608f * x * (1.f + 0.044715f * x * x);
    float e = __expf(2.f * fminf(u, 15.f));
    return x * e * __builtin_amdgcn_rcpf(e + 1.f);
}

__global__ void sentinel_kernel(float* o) { o[threadIdx.x] = 1e9f; }

// ---------------------------------------------------------------------------
__global__ void transpose_w(const float* __restrict__ w, bf16_t* __restrict__ wt,
                            int K, int N)
{
    int i = blockIdx.x * 256 + threadIdx.x;
    if (i >= K * N) return;
    int k = i / N, n = i % N;
    wt[(long)n * K + k] = __float2bfloat16(w[i]);
}

// ---------------------------------------------------------------------------
// Fully fused Swin attention half, v4 = R15 structure with 48 KB LDS:
// vT aliases xn (xn dead after phase-2 kt loop + barrier); attw aliases qkb
// (dead after kf/qf loads + barrier). 3 blocks/CU instead of 2.
// LDS: xnb 16 KB (later vtb[128][56]) | qkb 32 KB (later attw[49][152]).
// ---------------------------------------------------------------------------
__global__ __launch_bounds__(256) void swin_fused(const float* __restrict__ x,
                                                  const float* __restrict__ lng,
                                                  const float* __restrict__ lnb,
                                                  const bf16_t* __restrict__ qkvwt,
                                                  const float*  __restrict__ qkvb,
                                                  const float*  __restrict__ rpb,
                                                  const bf16_t* __restrict__ projwt,
                                                  const float*  __restrict__ projb,
                                                  bf16_t* __restrict__ y)
{
    __shared__ char smem[16384 + 32768];   // 48 KB
    char*   xnb = smem;                    // phase 1-2: LN1'd x; then vT
    char*   qkb = smem + 16384;            // q,k [64][512B] swizzled; then attw
    __bf16* vtb = (__bf16*)smem;           // [128][56] (14,336 B <= 16 KB)

    int win  = blockIdx.x;
    int tid  = threadIdx.x;
    int wave = tid >> 6;
    int lane = tid & 63;
    int la = lane & 15, lb = lane >> 4;

    // ---- phase 1: LN1 of window tokens -> xn ----
    {
        int row = wave * 16 + la;
        int tw  = win * 49 + row;
        if (tw > M_ - 1) tw = M_ - 1;      // rows >=49: finite, discarded
        long src = win_to_tok(tw);
        const float* xr = x + src * C_;
        float vals[4][8];
        float sm = 0.f, qs = 0.f;
#pragma unroll
        for (int kt = 0; kt < 4; ++kt) {
            f32x4 u0 = *reinterpret_cast<const f32x4*>(xr + kt * 32 + lb * 8);
            f32x4 u1 = *reinterpret_cast<const f32x4*>(xr + kt * 32 + lb * 8 + 4);
#pragma unroll
            for (int j = 0; j < 4; ++j) { vals[kt][j] = u0[j]; vals[kt][4 + j] = u1[j]; }
#pragma unroll
            for (int j = 0; j < 8; ++j) { sm += vals[kt][j]; qs += vals[kt][j] * vals[kt][j]; }
        }
        sm += __shfl_xor(sm, 16); sm += __shfl_xor(sm, 32);
        qs += __shfl_xor(qs, 16); qs += __shfl_xor(qs, 32);
        float mean = sm * (1.f / 128.f);
        float rstd = rsqrtf(qs * (1.f / 128.f) - mean * mean + 1e-5f);
#pragma unroll
        for (int kt = 0; kt < 4; ++kt) {
            bf16x8 v8;
#pragma unroll
            for (int j = 0; j < 8; ++j) {
                int col = kt * 32 + lb * 8 + j;
                v8[j] = (__bf16)((vals[kt][j] - mean) * rstd * lng[col] + lnb[col]);
            }
            int colb = kt * 64 + lb * 16;
            *reinterpret_cast<bf16x8*>(xnb + row * 256 + (colb ^ ((row & 7) << 4))) = v8;
        }
    }
    __syncthreads();

    // ---- phase 2: qkv, wave = 64 rows x 96 cols ----
    f32x4 acc[4][6];
    {
        int c0 = wave * 96;
#pragma unroll
        for (int nt = 0; nt < 6; ++nt) {
            float bv = qkvb[c0 + nt * 16 + la];
#pragma unroll
            for (int s = 0; s < 4; ++s) acc[s][nt] = (f32x4){bv, bv, bv, bv};
        }
#pragma unroll
        for (int kt = 0; kt < 4; ++kt) {
            bf16x8 ar[4];
#pragma unroll
            for (int s = 0; s < 4; ++s) {
                int row = s * 16 + la;
                ar[s] = *reinterpret_cast<const bf16x8*>(
                    xnb + row * 256 + ((kt * 64 + lb * 16) ^ ((row & 7) << 4)));
            }
#pragma unroll
            for (int nt = 0; nt < 6; ++nt) {
                bf16x8 br = *reinterpret_cast<const bf16x8*>(
                    qkvwt + (long)(c0 + nt * 16 + la) * 128 + kt * 32 + lb * 8);
#pragma unroll
                for (int s = 0; s < 4; ++s)
                    acc[s][nt] = __builtin_amdgcn_mfma_f32_16x16x32_bf16(
                        ar[s], br, acc[s][nt], 0, 0, 0);
            }
        }
    }
    __syncthreads();        // xn reads complete; xn region reusable as vT

    // ---- phase 2 epilogue: q,k -> qkb; v -> vtb (aliases xn); zero pads ----
    for (int i = tid; i < 128 * 7; i += 256)
        vtb[(i / 7) * 56 + 49 + i % 7] = (__bf16)0.f;
    {
        int c0 = wave * 96;
#pragma unroll
        for (int s = 0; s < 4; ++s) {
#pragma unroll
            for (int r = 0; r < 4; ++r) {
                int row = s * 16 + lb * 4 + r;     // window-local token = key
#pragma unroll
                for (int nt = 0; nt < 6; ++nt) {
                    int col = c0 + nt * 16 + la;
                    float v = acc[s][nt][r];
                    if (col < 256) {
                        *reinterpret_cast<__bf16*>(
                            qkb + row * 512 + ((col * 2) ^ ((row & 7) << 4))) = (__bf16)v;
                    } else if (row < 49) {
                        vtb[(col - 256) * 56 + row] = (__bf16)v;
                    }
                }
            }
        }
    }
    __syncthreads();

    // ---- phase 3: attention (wave = head h) ----
    int h = wave;
    bf16x8 kf[4], qf[4];
#pragma unroll
    for (int t = 0; t < 4; ++t) {
        int row = t * 16 + la;
        kf[t] = *reinterpret_cast<const bf16x8*>(
            qkb + row * 512 + ((256 + h * 64 + lb * 16) ^ ((row & 7) << 4)));
        qf[t] = *reinterpret_cast<const bf16x8*>(
            qkb + row * 512 + ((      h * 64 + lb * 16) ^ ((row & 7) << 4)));
    }
    __syncthreads();        // kf/qf loaded by all waves; qkb reusable as attw

    f32x4 S[4][4];
#pragma unroll
    for (int qt = 0; qt < 4; ++qt)
#pragma unroll
        for (int kt = 0; kt < 4; ++kt)
            S[qt][kt] = __builtin_amdgcn_mfma_f32_16x16x32_bf16(
                kf[kt], qf[qt], (f32x4){0.f, 0.f, 0.f, 0.f}, 0, 0, 0);

    const float scale = 0.17677669529663687f;   // 1/sqrt(32)
    int wi  = win & 63;
    int wh  = wi >> 3, wwp = wi & 7;
    bool edge = (wh == 7) || (wwp == 7);

    int i1[4], j1[4], r1[4], c1[4];
#pragma unroll
    for (int qt = 0; qt < 4; ++qt) {
        int q  = qt * 16 + la;
        int qc = q < 49 ? q : 48;
        i1[qt] = qc / 7; j1[qt] = qc - 7 * i1[qt];
        r1[qt] = (wh  < 7) ? 0 : ((i1[qt] < 4) ? 1 : 2);
        c1[qt] = (wwp < 7) ? 0 : ((j1[qt] < 4) ? 1 : 2);
    }

#pragma unroll
    for (int kt = 0; kt < 4; ++kt) {
#pragma unroll
        for (int r = 0; r < 4; ++r) {
            if (kt == 3 && r > 0) {
#pragma unroll
                for (int qt = 0; qt < 4; ++qt) S[qt][kt][r] = -1e30f;
                continue;
            }
            int key = kt * 16 + lb * 4 + r;
            int kc  = key < 49 ? key : 48;
            int i2  = kc / 7, j2 = kc - 7 * i2;
            int r2  = (wh  < 7) ? 0 : ((i2 < 4) ? 1 : 2);
            int c2  = (wwp < 7) ? 0 : ((j2 < 4) ? 1 : 2);
#pragma unroll
            for (int qt = 0; qt < 4; ++qt) {
                float bv  = rpb[(((i1[qt] - i2 + 6) * 13 + (j1[qt] - j2 + 6)) << 2) + h];
                float val = S[qt][kt][r] * scale + bv;
                if (edge && ((r1[qt] != r2) | (c1[qt] != c2))) val -= 100.f;
                if (kt == 3 && lb > 0) val = -1e30f;
                S[qt][kt][r] = val;
            }
        }
    }

    float inv[4];
#pragma unroll
    for (int qt = 0; qt < 4; ++qt) {
        float mx = -3e38f;
#pragma unroll
        for (int kt = 0; kt < 4; ++kt)
#pragma unroll
            for (int r = 0; r < 4; ++r) mx = fmaxf(mx, S[qt][kt][r]);
        mx = fmaxf(mx, __shfl_xor(mx, 16));
        mx = fmaxf(mx, __shfl_xor(mx, 32));
        float sm = 0.f;
#pragma unroll
        for (int kt = 0; kt < 4; ++kt)
#pragma unroll
            for (int r = 0; r < 4; ++r) {
                float e = __expf(S[qt][kt][r] - mx);
                S[qt][kt][r] = e;
                sm += e;
            }
        sm += __shfl_xor(sm, 16);
        sm += __shfl_xor(sm, 32);
        inv[qt] = 1.f / sm;
    }

    unsigned int w_[4][4][2];
#pragma unroll
    for (int qt = 0; qt < 4; ++qt)
#pragma unroll
        for (int t = 0; t < 4; ++t) {
            w_[qt][t][0] = pk2(S[qt][t][0], S[qt][t][1]);
            w_[qt][t][1] = pk2(S[qt][t][2], S[qt][t][3]);
        }

    int srcA = la + (((2 * lb)     & 3) << 4);
    int srcB = la + (((2 * lb + 1) & 3) << 4);
    bool hiT = (lb >> 1) & 1;

    f32x4 O[2][4];
#pragma unroll
    for (int dt = 0; dt < 2; ++dt)
#pragma unroll
        for (int qt = 0; qt < 4; ++qt) O[dt][qt] = (f32x4){0.f, 0.f, 0.f, 0.f};

#pragma unroll
    for (int kk = 0; kk < 2; ++kk) {
        bf16x8 vf[2];
#pragma unroll
        for (int dt = 0; dt < 2; ++dt)
            vf[dt] = *reinterpret_cast<const bf16x8*>(
                vtb + (h * 32 + dt * 16 + la) * 56 + kk * 32 + lb * 8);
        int tl = kk * 2;
#pragma unroll
        for (int qt = 0; qt < 4; ++qt) {
            unsigned int a0 = __shfl(w_[qt][tl][0],     srcA);
            unsigned int b0 = __shfl(w_[qt][tl + 1][0], srcA);
            unsigned int a1 = __shfl(w_[qt][tl][1],     srcA);
            unsigned int b1 = __shfl(w_[qt][tl + 1][1], srcA);
            unsigned int a2 = __shfl(w_[qt][tl][0],     srcB);
            unsigned int b2 = __shfl(w_[qt][tl + 1][0], srcB);
            unsigned int a3 = __shfl(w_[qt][tl][1],     srcB);
            unsigned int b3 = __shfl(w_[qt][tl + 1][1], srcB);
            u32x4 uu = { hiT ? b0 : a0, hiT ? b1 : a1, hiT ? b2 : a2, hiT ? b3 : a3 };
            bf16x8 pf = __builtin_bit_cast(bf16x8, uu);
#pragma unroll
            for (int dt = 0; dt < 2; ++dt)
                O[dt][qt] = __builtin_amdgcn_mfma_f32_16x16x32_bf16(vf[dt], pf, O[dt][qt], 0, 0, 0);
        }
    }

    // ---- normalized O -> attw (aliases qkb; safe after kf/qf barrier) ----
    __bf16 (*attw)[152] = (__bf16(*)[152])qkb;
#pragma unroll
    for (int qt = 0; qt < 4; ++qt) {
        int q = qt * 16 + la;
        if (q < 49) {
            float iv = inv[qt];
#pragma unroll
            for (int dt = 0; dt < 2; ++dt) {
                unsigned int s0 = pk2(O[dt][qt][0] * iv, O[dt][qt][1] * iv);
                unsigned int s1 = pk2(O[dt][qt][2] * iv, O[dt][qt][3] * iv);
                uint2 st = {s0, s1};
                *reinterpret_cast<uint2*>(&attw[q][h * 32 + dt * 16 + lb * 4]) = st;
            }
        }
    }
    __syncthreads();

    // ---- phase 4: proj, wave h = cols h*32..h*32+31 ----
    int n0 = h * 32;
    f32x4 pacc[4][2];
#pragma unroll
    for (int nt = 0; nt < 2; ++nt) {
        float bv = projb[n0 + nt * 16 + la];
#pragma unroll
        for (int s = 0; s < 4; ++s) pacc[s][nt] = (f32x4){bv, bv, bv, bv};
    }
#pragma unroll
    for (int kt = 0; kt < 4; ++kt) {
        bf16x8 ar[4];
#pragma unroll
        for (int s = 0; s < 4; ++s)
            ar[s] = *reinterpret_cast<const bf16x8*>(&attw[s * 16 + la][kt * 32 + lb * 8]);
#pragma unroll
        for (int nt = 0; nt < 2; ++nt) {
            bf16x8 br = *reinterpret_cast<const bf16x8*>(
                projwt + (long)(n0 + nt * 16 + la) * 128 + kt * 32 + lb * 8);
#pragma unroll
            for (int s = 0; s < 4; ++s)
                pacc[s][nt] = __builtin_amdgcn_mfma_f32_16x16x32_bf16(
                    ar[s], br, pacc[s][nt], 0, 0, 0);
        }
    }

    // ---- epilogue: window-reverse + unshift + x residual -> bf16 y ----
#pragma unroll
    for (int s = 0; s < 4; ++s) {
#pragma unroll
        for (int r = 0; r < 4; ++r) {
            int q = s * 16 + lb * 4 + r;
            if (q < 49) {
                long to = win_to_tok(win * 49 + q);
#pragma unroll
                for (int nt = 0; nt < 2; ++nt) {
                    int col = n0 + nt * 16 + la;
                    y[to * C_ + col] =
                        __float2bfloat16(pacc[s][nt][r] + x[to * C_ + col]);
                }
            }
        }
    }
}

// ---------------------------------------------------------------------------
// Fused MLP v8 (unchanged): bf16 y, 512-thread blocks, single 32 KB LDS
// weight buffer, XOR-swizzled rows. out (f32) written once.
// ---------------------------------------------------------------------------
__global__ __launch_bounds__(512, 4) void mlp_fused(const bf16_t* __restrict__ y,
                                                    const float* __restrict__ g,
                                                    const float* __restrict__ b,
                                                    const bf16_t* __restrict__ w1t,
                                                    const float* __restrict__ b1,
                                                    const bf16_t* __restrict__ w2t,
                                                    const float* __restrict__ b2,
                                                    float* __restrict__ out)
{
    __shared__ uint4 ldsq[2048];             // 32 KB: [W1c 16KB | W2c 16KB]
    int tid  = threadIdx.x;
    int lane = tid & 63;
    int la = lane & 15, lb = lane >> 4;
    int m0 = (blockIdx.x * 8 + (tid >> 6)) * 32;

    auto stage = [&](int c) {
        char* d1 = (char*)&ldsq[0];
        const char* s1 = (const char*)w1t + (size_t)c * 16384;
#pragma unroll
        for (int i = 0; i < 2; ++i) {
            int idx = i * 512 + tid;             // 0..1023, 16B units
            int row = idx >> 4, colb = (idx & 15) * 16;
            uint4 v = *reinterpret_cast<const uint4*>(s1 + idx * 16);
            *reinterpret_cast<uint4*>(d1 + row * 256 + (colb ^ ((row & 7) << 4))) = v;
        }
        char* d2 = (char*)&ldsq[1024];
        const char* s2 = (const char*)w2t + (size_t)c * 128;
#pragma unroll
        for (int i = 0; i < 2; ++i) {
            int idx = i * 512 + tid;             // 0..1023
            int row = idx >> 3, colb = (idx & 7) * 16;
            uint4 v = *reinterpret_cast<const uint4*>(s2 + (size_t)row * 1024 + colb);
            *reinterpret_cast<uint4*>(d2 + row * 128 + (colb ^ ((row & 7) << 4))) = v;
        }
    };

    // ---- LN2 -> fragments for 2 row-subtiles ----
    bf16x8 af[2][4];
#pragma unroll
    for (int s = 0; s < 2; ++s) {
        const bf16_t* yr = y + (long)(m0 + s * 16 + la) * C_;
        float vals[4][8];
        float sm = 0.f, qs = 0.f;
#pragma unroll
        for (int kt = 0; kt < 4; ++kt) {
            bf16x8 v8 = *reinterpret_cast<const bf16x8*>(yr + kt * 32 + lb * 8);
#pragma unroll
            for (int j = 0; j < 8; ++j) {
                float v = (float)v8[j];
                vals[kt][j] = v; sm += v; qs += v * v;
            }
        }
        sm += __shfl_xor(sm, 16); sm += __shfl_xor(sm, 32);
        qs += __shfl_xor(qs, 16); qs += __shfl_xor(qs, 32);
        float mean = sm * (1.f / 128.f);
        float rstd = rsqrtf(qs * (1.f / 128.f) - mean * mean + 1e-5f);
#pragma unroll
        for (int kt = 0; kt < 4; ++kt)
#pragma unroll
            for (int j = 0; j < 8; ++j) {
                int col = kt * 32 + lb * 8 + j;
                af[s][kt][j] = (__bf16)((vals[kt][j] - mean) * rstd * g[col] + b[col]);
            }
    }

    f32x4 acc[2][8];
#pragma unroll
    for (int nt2 = 0; nt2 < 8; ++nt2) {
        f32x4 bv = *reinterpret_cast<const f32x4*>(b2 + nt2 * 16 + lb * 4);
#pragma unroll
        for (int s = 0; s < 2; ++s) acc[s][nt2] = bv;
    }

    int srcA = la + (((2 * lb)     & 3) << 4);
    int srcB = la + (((2 * lb + 1) & 3) << 4);
    bool hiT = (lb >> 1) & 1;

    for (int c = 0; c < 8; ++c) {
        stage(c);
        __syncthreads();

        const char* L1 = (const char*)&ldsq[0];
        const char* L2 = (const char*)&ldsq[1024];

        f32x4 hacc[2][4];
#pragma unroll
        for (int nt = 0; nt < 4; ++nt) {
            f32x4 bv = *reinterpret_cast<const f32x4*>(b1 + c * 64 + nt * 16 + lb * 4);
#pragma unroll
            for (int s = 0; s < 2; ++s) hacc[s][nt] = bv;
        }
#pragma unroll
        for (int kt = 0; kt < 4; ++kt)
#pragma unroll
            for (int nt = 0; nt < 4; ++nt) {
                int row = nt * 16 + la;
                bf16x8 w1f = *reinterpret_cast<const bf16x8*>(
                    L1 + row * 256 + ((kt * 64 + lb * 16) ^ ((row & 7) << 4)));
#pragma unroll
                for (int s = 0; s < 2; ++s)
                    hacc[s][nt] = __builtin_amdgcn_mfma_f32_16x16x32_bf16(
                        w1f, af[s][kt], hacc[s][nt], 0, 0, 0);
            }
        unsigned int wpk[2][4][2];
#pragma unroll
        for (int s = 0; s < 2; ++s)
#pragma unroll
            for (int t = 0; t < 4; ++t) {
                f32x4 hv = hacc[s][t];
#pragma unroll
                for (int r = 0; r < 4; ++r) hv[r] = gelu_f(hv[r]);
                wpk[s][t][0] = pk2(hv[0], hv[1]);
                wpk[s][t][1] = pk2(hv[2], hv[3]);
            }
#pragma unroll
        for (int kk = 0; kk < 2; ++kk) {
            int tl = kk * 2;
#pragma unroll
            for (int s = 0; s < 2; ++s) {
                unsigned int a0 = __shfl(wpk[s][tl][0],     srcA);
                unsigned int b0 = __shfl(wpk[s][tl + 1][0], srcA);
                unsigned int a1 = __shfl(wpk[s][tl][1],     srcA);
                unsigned int b1v = __shfl(wpk[s][tl + 1][1], srcA);
                unsigned int a2 = __shfl(wpk[s][tl][0],     srcB);
                unsigned int b2v = __shfl(wpk[s][tl + 1][0], srcB);
                unsigned int a3 = __shfl(wpk[s][tl][1],     srcB);
                unsigned int b3v = __shfl(wpk[s][tl + 1][1], srcB);
                u32x4 uu = { hiT ? b0 : a0, hiT ? b1v : a1, hiT ? b2v : a2, hiT ? b3v : a3 };
                bf16x8 pf = __builtin_bit_cast(bf16x8, uu);
#pragma unroll
                for (int nt2 = 0; nt2 < 8; ++nt2) {
                    int row2 = nt2 * 16 + la;
                    bf16x8 w2f = *reinterpret_cast<const bf16x8*>(
                        L2 + row2 * 128 + ((kk * 64 + lb * 16) ^ ((row2 & 7) << 4)));
                    acc[s][nt2] = __builtin_amdgcn_mfma_f32_16x16x32_bf16(
                        w2f, pf, acc[s][nt2], 0, 0, 0);
                }
            }
        }
        __syncthreads();
    }

    // ---- epilogue: + y residual (bf16) -> f32 out ----
#pragma unroll
    for (int s = 0; s < 2; ++s) {
        long m = m0 + s * 16 + la;
        const bf16_t* yrow = y + m * C_;
        float* orow = out + m * C_;
#pragma unroll
        for (int nt2 = 0; nt2 < 8; ++nt2) {
            int n2 = nt2 * 16 + lb * 4;
            bf16x4 rb = *reinterpret_cast<const bf16x4*>(yrow + n2);
            f32x4 val = acc[s][nt2];
#pragma unroll
            for (int r = 0; r < 4; ++r) val[r] += (float)rb[r];
            *reinterpret_cast<f32x4*>(orow + n2) = val;
        }
    }
}

// ---------------------------------------------------------------------------
extern "C" void kernel_launch(void* const* d_in, const int* in_sizes, int n_in,
                              void* d_out, int out_size, void* d_ws, size_t ws_size,
                              hipStream_t stream)
{
    (void)in_sizes; (void)n_in; (void)out_size;

    const float* x      = (const float*)d_in[0];
    const float* n1g    = (const float*)d_in[1];
    const float* n1b    = (const float*)d_in[2];
    const float* qkv_w  = (const float*)d_in[3];
    const float* qkv_b  = (const float*)d_in[4];
    const float* proj_w = (const float*)d_in[5];
    const float* proj_b = (const float*)d_in[6];
    const float* rpb    = (const float*)d_in[7];
    const float* n2g    = (const float*)d_in[8];
    const float* n2b    = (const float*)d_in[9];
    const float* fc1_w  = (const float*)d_in[10];
    const float* fc1_b  = (const float*)d_in[11];
    const float* fc2_w  = (const float*)d_in[12];
    const float* fc2_b  = (const float*)d_in[13];

    char* ws = (char*)d_ws;

    const size_t yb_sz = (size_t)M_ * 128 * 2;               // 51,380,224 (bf16 y)
    const size_t w_sz  = (size_t)(128 * 384 + 128 * 128 + 128 * 512 + 512 * 128) * 2;
    const size_t need  = yb_sz + w_sz;                       // ~51.8 MB

    if (need > ws_size) {
        sentinel_kernel<<<1, 256, 0, stream>>>((float*)d_out);
        return;
    }

    bf16_t* yb      = (bf16_t*)ws;
    bf16_t* qkv_wt  = (bf16_t*)(ws + yb_sz);
    bf16_t* proj_wt = qkv_wt + 128 * 384;
    bf16_t* fc1_wt  = proj_wt + 128 * 128;
    bf16_t* fc2_wt  = fc1_wt + 128 * 512;

    transpose_w<<<(128 * 384 + 255) / 256, 256, 0, stream>>>(qkv_w, qkv_wt, 128, 384);
    transpose_w<<<(128 * 128 + 255) / 256, 256, 0, stream>>>(proj_w, proj_wt, 128, 128);
    transpose_w<<<(128 * 512 + 255) / 256, 256, 0, stream>>>(fc1_w, fc1_wt, 128, 512);
    transpose_w<<<(512 * 128 + 255) / 256, 256, 0, stream>>>(fc2_w, fc2_wt, 512, 128);

    // LN1 + qkv + attention + proj + window-reverse + residual -> bf16 y
    swin_fused<<<NWIN, 256, 0, stream>>>(x, n1g, n1b, qkv_wt, qkv_b, rpb,
                                         proj_wt, proj_b, yb);
    // LN2 + fc1 + GELU + fc2 + residual -> f32 d_out
    mlp_fused<<<M_ / 256, 512, 0, stream>>>(
        yb, n2g, n2b, fc1_wt, fc1_b, fc2_wt, fc2_b, (float*)d_out);
}

// Round 19
// 401.302 us; speedup vs baseline: 1.2176x; 1.2176x over previous
//
#include <hip/hip_runtime.h>
#include <hip/hip_bf16.h>
#include <math.h>

typedef __bf16 bf16x8 __attribute__((ext_vector_type(8)));
typedef __bf16 bf16x4 __attribute__((ext_vector_type(4)));
typedef float  f32x4  __attribute__((ext_vector_type(4)));
typedef unsigned int u32x4 __attribute__((ext_vector_type(4)));
typedef __hip_bfloat16 bf16_t;

static constexpr int C_    = 128;
static constexpr int L_    = 56 * 56;        // tokens per image
static constexpr int M_    = 64 * L_;        // 200704 total tokens
static constexpr int NWIN  = 64 * 64;        // 4096 windows

// map windowed token index tw -> unwindowed token index (shift+window bijection)
__device__ inline long win_to_tok(int tw)
{
    int win = tw / 49, n = tw % 49;
    int bb  = win >> 6, wi = win & 63;
    int wh  = wi >> 3, wwp = wi & 7;
    int hs  = wh * 7 + n / 7;
    int wsv = wwp * 7 + n % 7;
    int hh  = (hs + 3) % 56;          // un-shift
    int ww  = (wsv + 3) % 56;
    return (long)bb * L_ + hh * 56 + ww;
}

__device__ inline unsigned int pk2(float lo, float hi)
{
    unsigned short a = __builtin_bit_cast(unsigned short, (__bf16)lo);
    unsigned short b = __builtin_bit_cast(unsigned short, (__bf16)hi);
    return (unsigned int)a | ((unsigned int)b << 16);
}

// tanh-form GELU: ~8 VALU ops, |err| <= ~3e-3 (threshold is 0.11).
__device__ inline float gelu_f(float x)
{
    float u = 0.7978845608f * x * (1.f + 0.044715f * x * x);
    float e = __expf(2.f * fminf(u, 15.f));
    return x * e * __builtin_amdgcn_rcpf(e + 1.f);
}

__global__ void sentinel_kernel(float* o) { o[threadIdx.x] = 1e9f; }

// ---------------------------------------------------------------------------
__global__ void transpose_w(const float* __restrict__ w, bf16_t* __restrict__ wt,
                            int K, int N)
{
    int i = blockIdx.x * 256 + threadIdx.x;
    if (i >= K * N) return;
    int k = i / N, n = i % N;
    wt[(long)n * K + k] = __float2bfloat16(w[i]);
}

// ---------------------------------------------------------------------------
// Fully fused Swin attention half (R15 version, verbatim — proven 258 us):
// LN1 + qkv + windowed attention + proj + window-reverse + x residual,
// one block per window (4 waves = 4 heads).
// LDS: xn[64][256B] (aliased by attw[49][152] after phase 2) |
//      qk[64][512B] XOR-swizzled | vT[128][56] bf16 (pads zeroed).
// ---------------------------------------------------------------------------
__global__ __launch_bounds__(256) void swin_fused(const float* __restrict__ x,
                                                  const float* __restrict__ lng,
                                                  const float* __restrict__ lnb,
                                                  const bf16_t* __restrict__ qkvwt,
                                                  const float*  __restrict__ qkvb,
                                                  const float*  __restrict__ rpb,
                                                  const bf16_t* __restrict__ projwt,
                                                  const float*  __restrict__ projb,
                                                  bf16_t* __restrict__ y)
{
    __shared__ char smem[16384 + 32768 + 14336];   // 63.5 KB
    char*   xnb = smem;                    // phase 1-2: LN1'd x; phase 3+: attw
    char*   qkb = smem + 16384;            // [64 rows][512 B], swizzled
    __bf16* vtb = (__bf16*)(smem + 49152); // [128][56]

    int win  = blockIdx.x;
    int tid  = threadIdx.x;
    int wave = tid >> 6;
    int lane = tid & 63;
    int la = lane & 15, lb = lane >> 4;

    // zero vT pad keys 49..55 (NaN safety: P[pad]=0 x V[pad] must be 0)
    for (int i = tid; i < 128 * 7; i += 256)
        vtb[(i / 7) * 56 + 49 + i % 7] = (__bf16)0.f;

    // ---- phase 1: LN1 of window tokens -> xn ----
    {
        int row = wave * 16 + la;
        int tw  = win * 49 + row;
        if (tw > M_ - 1) tw = M_ - 1;      // rows >=49 duplicate data, discarded
        long src = win_to_tok(tw);
        const float* xr = x + src * C_;
        float vals[4][8];
        float sm = 0.f, qs = 0.f;
#pragma unroll
        for (int kt = 0; kt < 4; ++kt) {
            f32x4 u0 = *reinterpret_cast<const f32x4*>(xr + kt * 32 + lb * 8);
            f32x4 u1 = *reinterpret_cast<const f32x4*>(xr + kt * 32 + lb * 8 + 4);
#pragma unroll
            for (int j = 0; j < 4; ++j) { vals[kt][j] = u0[j]; vals[kt][4 + j] = u1[j]; }
#pragma unroll
            for (int j = 0; j < 8; ++j) { sm += vals[kt][j]; qs += vals[kt][j] * vals[kt][j]; }
        }
        sm += __shfl_xor(sm, 16); sm += __shfl_xor(sm, 32);
        qs += __shfl_xor(qs, 16); qs += __shfl_xor(qs, 32);
        float mean = sm * (1.f / 128.f);
        float rstd = rsqrtf(qs * (1.f / 128.f) - mean * mean + 1e-5f);
#pragma unroll
        for (int kt = 0; kt < 4; ++kt) {
            bf16x8 v8;
#pragma unroll
            for (int j = 0; j < 8; ++j) {
                int col = kt * 32 + lb * 8 + j;
                v8[j] = (__bf16)((vals[kt][j] - mean) * rstd * lng[col] + lnb[col]);
            }
            int colb = kt * 64 + lb * 16;
            *reinterpret_cast<bf16x8*>(xnb + row * 256 + (colb ^ ((row & 7) << 4))) = v8;
        }
    }
    __syncthreads();

    // ---- phase 2: qkv, wave = 64 rows x 96 cols; outputs -> LDS ----
    {
        int c0 = wave * 96;
        f32x4 acc[4][6];
#pragma unroll
        for (int nt = 0; nt < 6; ++nt) {
            float bv = qkvb[c0 + nt * 16 + la];
#pragma unroll
            for (int s = 0; s < 4; ++s) acc[s][nt] = (f32x4){bv, bv, bv, bv};
        }
#pragma unroll
        for (int kt = 0; kt < 4; ++kt) {
            bf16x8 ar[4];
#pragma unroll
            for (int s = 0; s < 4; ++s) {
                int row = s * 16 + la;
                ar[s] = *reinterpret_cast<const bf16x8*>(
                    xnb + row * 256 + ((kt * 64 + lb * 16) ^ ((row & 7) << 4)));
            }
#pragma unroll
            for (int nt = 0; nt < 6; ++nt) {
                bf16x8 br = *reinterpret_cast<const bf16x8*>(
                    qkvwt + (long)(c0 + nt * 16 + la) * 128 + kt * 32 + lb * 8);
#pragma unroll
                for (int s = 0; s < 4; ++s)
                    acc[s][nt] = __builtin_amdgcn_mfma_f32_16x16x32_bf16(
                        ar[s], br, acc[s][nt], 0, 0, 0);
            }
        }
        // epilogue -> LDS (q,k swizzled rows; v transposed, key<49 only)
#pragma unroll
        for (int s = 0; s < 4; ++s) {
#pragma unroll
            for (int r = 0; r < 4; ++r) {
                int row = s * 16 + lb * 4 + r;     // window-local token = key
#pragma unroll
                for (int nt = 0; nt < 6; ++nt) {
                    int col = c0 + nt * 16 + la;
                    float v = acc[s][nt][r];
                    if (col < 256) {
                        *reinterpret_cast<__bf16*>(
                            qkb + row * 512 + ((col * 2) ^ ((row & 7) << 4))) = (__bf16)v;
                    } else if (row < 49) {
                        vtb[(col - 256) * 56 + row] = (__bf16)v;
                    }
                }
            }
        }
    }
    __syncthreads();

    // ---- phase 3: attention (wave = head h) ----
    int h = wave;
    bf16x8 kf[4], qf[4];
#pragma unroll
    for (int t = 0; t < 4; ++t) {
        int row = t * 16 + la;
        kf[t] = *reinterpret_cast<const bf16x8*>(
            qkb + row * 512 + ((256 + h * 64 + lb * 16) ^ ((row & 7) << 4)));
        qf[t] = *reinterpret_cast<const bf16x8*>(
            qkb + row * 512 + ((      h * 64 + lb * 16) ^ ((row & 7) << 4)));
    }

    f32x4 S[4][4];
#pragma unroll
    for (int qt = 0; qt < 4; ++qt)
#pragma unroll
        for (int kt = 0; kt < 4; ++kt)
            S[qt][kt] = __builtin_amdgcn_mfma_f32_16x16x32_bf16(
                kf[kt], qf[qt], (f32x4){0.f, 0.f, 0.f, 0.f}, 0, 0, 0);

    const float scale = 0.17677669529663687f;   // 1/sqrt(32)
    int wi  = win & 63;
    int wh  = wi >> 3, wwp = wi & 7;
    bool edge = (wh == 7) || (wwp == 7);

    int i1[4], j1[4], r1[4], c1[4];
#pragma unroll
    for (int qt = 0; qt < 4; ++qt) {
        int q  = qt * 16 + la;
        int qc = q < 49 ? q : 48;
        i1[qt] = qc / 7; j1[qt] = qc - 7 * i1[qt];
        r1[qt] = (wh  < 7) ? 0 : ((i1[qt] < 4) ? 1 : 2);
        c1[qt] = (wwp < 7) ? 0 : ((j1[qt] < 4) ? 1 : 2);
    }

#pragma unroll
    for (int kt = 0; kt < 4; ++kt) {
#pragma unroll
        for (int r = 0; r < 4; ++r) {
            if (kt == 3 && r > 0) {
#pragma unroll
                for (int qt = 0; qt < 4; ++qt) S[qt][kt][r] = -1e30f;
                continue;
            }
            int key = kt * 16 + lb * 4 + r;
            int kc  = key < 49 ? key : 48;
            int i2  = kc / 7, j2 = kc - 7 * i2;
            int r2  = (wh  < 7) ? 0 : ((i2 < 4) ? 1 : 2);
            int c2  = (wwp < 7) ? 0 : ((j2 < 4) ? 1 : 2);
#pragma unroll
            for (int qt = 0; qt < 4; ++qt) {
                float bv  = rpb[(((i1[qt] - i2 + 6) * 13 + (j1[qt] - j2 + 6)) << 2) + h];
                float val = S[qt][kt][r] * scale + bv;
                if (edge && ((r1[qt] != r2) | (c1[qt] != c2))) val -= 100.f;
                if (kt == 3 && lb > 0) val = -1e30f;
                S[qt][kt][r] = val;
            }
        }
    }

    float inv[4];
#pragma unroll
    for (int qt = 0; qt < 4; ++qt) {
        float mx = -3e38f;
#pragma unroll
        for (int kt = 0; kt < 4; ++kt)
#pragma unroll
            for (int r = 0; r < 4; ++r) mx = fmaxf(mx, S[qt][kt][r]);
        mx = fmaxf(mx, __shfl_xor(mx, 16));
        mx = fmaxf(mx, __shfl_xor(mx, 32));
        float sm = 0.f;
#pragma unroll
        for (int kt = 0; kt < 4; ++kt)
#pragma unroll
            for (int r = 0; r < 4; ++r) {
                float e = __expf(S[qt][kt][r] - mx);
                S[qt][kt][r] = e;
                sm += e;
            }
        sm += __shfl_xor(sm, 16);
        sm += __shfl_xor(sm, 32);
        inv[qt] = 1.f / sm;
    }

    unsigned int w_[4][4][2];
#pragma unroll
    for (int qt = 0; qt < 4; ++qt)
#pragma unroll
        for (int t = 0; t < 4; ++t) {
            w_[qt][t][0] = pk2(S[qt][t][0], S[qt][t][1]);
            w_[qt][t][1] = pk2(S[qt][t][2], S[qt][t][3]);
        }

    int srcA = la + (((2 * lb)     & 3) << 4);
    int srcB = la + (((2 * lb + 1) & 3) << 4);
    bool hiT = (lb >> 1) & 1;

    f32x4 O[2][4];
#pragma unroll
    for (int dt = 0; dt < 2; ++dt)
#pragma unroll
        for (int qt = 0; qt < 4; ++qt) O[dt][qt] = (f32x4){0.f, 0.f, 0.f, 0.f};

#pragma unroll
    for (int kk = 0; kk < 2; ++kk) {
        bf16x8 vf[2];
#pragma unroll
        for (int dt = 0; dt < 2; ++dt)
            vf[dt] = *reinterpret_cast<const bf16x8*>(
                vtb + (h * 32 + dt * 16 + la) * 56 + kk * 32 + lb * 8);
        int tl = kk * 2;
#pragma unroll
        for (int qt = 0; qt < 4; ++qt) {
            unsigned int a0 = __shfl(w_[qt][tl][0],     srcA);
            unsigned int b0 = __shfl(w_[qt][tl + 1][0], srcA);
            unsigned int a1 = __shfl(w_[qt][tl][1],     srcA);
            unsigned int b1 = __shfl(w_[qt][tl + 1][1], srcA);
            unsigned int a2 = __shfl(w_[qt][tl][0],     srcB);
            unsigned int b2 = __shfl(w_[qt][tl + 1][0], srcB);
            unsigned int a3 = __shfl(w_[qt][tl][1],     srcB);
            unsigned int b3 = __shfl(w_[qt][tl + 1][1], srcB);
            u32x4 uu = { hiT ? b0 : a0, hiT ? b1 : a1, hiT ? b2 : a2, hiT ? b3 : a3 };
            bf16x8 pf = __builtin_bit_cast(bf16x8, uu);
#pragma unroll
            for (int dt = 0; dt < 2; ++dt)
                O[dt][qt] = __builtin_amdgcn_mfma_f32_16x16x32_bf16(vf[dt], pf, O[dt][qt], 0, 0, 0);
        }
    }

    // ---- normalized O -> attw (aliases xn; xn dead since phase-2 barrier) ----
    __bf16 (*attw)[152] = (__bf16(*)[152])xnb;
#pragma unroll
    for (int qt = 0; qt < 4; ++qt) {
        int q = qt * 16 + la;
        if (q < 49) {
            float iv = inv[qt];
#pragma unroll
            for (int dt = 0; dt < 2; ++dt) {
                unsigned int s0 = pk2(O[dt][qt][0] * iv, O[dt][qt][1] * iv);
                unsigned int s1 = pk2(O[dt][qt][2] * iv, O[dt][qt][3] * iv);
                uint2 st = {s0, s1};
                *reinterpret_cast<uint2*>(&attw[q][h * 32 + dt * 16 + lb * 4]) = st;
            }
        }
    }
    __syncthreads();

    // ---- phase 4: proj, wave h computes C[q=0..63][n=h*32..h*32+31] ----
    int n0 = h * 32;
    f32x4 pacc[4][2];
#pragma unroll
    for (int nt = 0; nt < 2; ++nt) {
        float bv = projb[n0 + nt * 16 + la];
#pragma unroll
        for (int s = 0; s < 4; ++s) pacc[s][nt] = (f32x4){bv, bv, bv, bv};
    }
#pragma unroll
    for (int kt = 0; kt < 4; ++kt) {
        bf16x8 ar[4];
#pragma unroll
        for (int s = 0; s < 4; ++s)
            ar[s] = *reinterpret_cast<const bf16x8*>(&attw[s * 16 + la][kt * 32 + lb * 8]);
#pragma unroll
        for (int nt = 0; nt < 2; ++nt) {
            bf16x8 br = *reinterpret_cast<const bf16x8*>(
                projwt + (long)(n0 + nt * 16 + la) * 128 + kt * 32 + lb * 8);
#pragma unroll
            for (int s = 0; s < 4; ++s)
                pacc[s][nt] = __builtin_amdgcn_mfma_f32_16x16x32_bf16(
                    ar[s], br, pacc[s][nt], 0, 0, 0);
        }
    }

    // ---- epilogue: window-reverse + unshift + x residual -> bf16 y ----
#pragma unroll
    for (int s = 0; s < 4; ++s) {
#pragma unroll
        for (int r = 0; r < 4; ++r) {
            int q = s * 16 + lb * 4 + r;
            if (q < 49) {
                long to = win_to_tok(win * 49 + q);
#pragma unroll
                for (int nt = 0; nt < 2; ++nt) {
                    int col = n0 + nt * 16 + la;
                    y[to * C_ + col] =
                        __float2bfloat16(pacc[s][nt][r] + x[to * C_ + col]);
                }
            }
        }
    }
}

// ---------------------------------------------------------------------------
// Fused MLP v9: v8 per-wave code with 1024-thread blocks (16 waves, 512
// rows) -> half the blocks -> half the weight-staging L2/L3 traffic.
// Single 32 KB LDS buffer, stage -> barrier -> compute -> barrier per chunk.
// ---------------------------------------------------------------------------
__global__ __launch_bounds__(1024, 2) void mlp_fused(const bf16_t* __restrict__ y,
                                                     const float* __restrict__ g,
                                                     const float* __restrict__ b,
                                                     const bf16_t* __restrict__ w1t,
                                                     const float* __restrict__ b1,
                                                     const bf16_t* __restrict__ w2t,
                                                     const float* __restrict__ b2,
                                                     float* __restrict__ out)
{
    __shared__ uint4 ldsq[2048];             // 32 KB: [W1c 16KB | W2c 16KB]
    int tid  = threadIdx.x;
    int lane = tid & 63;
    int la = lane & 15, lb = lane >> 4;
    int m0 = (blockIdx.x * 16 + (tid >> 6)) * 32;

    auto stage = [&](int c) {
        {
            char* d1 = (char*)&ldsq[0];
            const char* s1 = (const char*)w1t + (size_t)c * 16384;
            int idx = tid;                       // 0..1023, 16B units
            int row = idx >> 4, colb = (idx & 15) * 16;
            uint4 v = *reinterpret_cast<const uint4*>(s1 + idx * 16);
            *reinterpret_cast<uint4*>(d1 + row * 256 + (colb ^ ((row & 7) << 4))) = v;
        }
        {
            char* d2 = (char*)&ldsq[1024];
            const char* s2 = (const char*)w2t + (size_t)c * 128;
            int idx = tid;                       // 0..1023
            int row = idx >> 3, colb = (idx & 7) * 16;
            uint4 v = *reinterpret_cast<const uint4*>(s2 + (size_t)row * 1024 + colb);
            *reinterpret_cast<uint4*>(d2 + row * 128 + (colb ^ ((row & 7) << 4))) = v;
        }
    };

    // ---- LN2 -> fragments for 2 row-subtiles ----
    bf16x8 af[2][4];
#pragma unroll
    for (int s = 0; s < 2; ++s) {
        const bf16_t* yr = y + (long)(m0 + s * 16 + la) * C_;
        float vals[4][8];
        float sm = 0.f, qs = 0.f;
#pragma unroll
        for (int kt = 0; kt < 4; ++kt) {
            bf16x8 v8 = *reinterpret_cast<const bf16x8*>(yr + kt * 32 + lb * 8);
#pragma unroll
            for (int j = 0; j < 8; ++j) {
                float v = (float)v8[j];
                vals[kt][j] = v; sm += v; qs += v * v;
            }
        }
        sm += __shfl_xor(sm, 16); sm += __shfl_xor(sm, 32);
        qs += __shfl_xor(qs, 16); qs += __shfl_xor(qs, 32);
        float mean = sm * (1.f / 128.f);
        float rstd = rsqrtf(qs * (1.f / 128.f) - mean * mean + 1e-5f);
#pragma unroll
        for (int kt = 0; kt < 4; ++kt)
#pragma unroll
            for (int j = 0; j < 8; ++j) {
                int col = kt * 32 + lb * 8 + j;
                af[s][kt][j] = (__bf16)((vals[kt][j] - mean) * rstd * g[col] + b[col]);
            }
    }

    f32x4 acc[2][8];
#pragma unroll
    for (int nt2 = 0; nt2 < 8; ++nt2) {
        f32x4 bv = *reinterpret_cast<const f32x4*>(b2 + nt2 * 16 + lb * 4);
#pragma unroll
        for (int s = 0; s < 2; ++s) acc[s][nt2] = bv;
    }

    int srcA = la + (((2 * lb)     & 3) << 4);
    int srcB = la + (((2 * lb + 1) & 3) << 4);
    bool hiT = (lb >> 1) & 1;

    for (int c = 0; c < 8; ++c) {
        stage(c);
        __syncthreads();

        const char* L1 = (const char*)&ldsq[0];
        const char* L2 = (const char*)&ldsq[1024];

        f32x4 hacc[2][4];
#pragma unroll
        for (int nt = 0; nt < 4; ++nt) {
            f32x4 bv = *reinterpret_cast<const f32x4*>(b1 + c * 64 + nt * 16 + lb * 4);
#pragma unroll
            for (int s = 0; s < 2; ++s) hacc[s][nt] = bv;
        }
#pragma unroll
        for (int kt = 0; kt < 4; ++kt)
#pragma unroll
            for (int nt = 0; nt < 4; ++nt) {
                int row = nt * 16 + la;
                bf16x8 w1f = *reinterpret_cast<const bf16x8*>(
                    L1 + row * 256 + ((kt * 64 + lb * 16) ^ ((row & 7) << 4)));
#pragma unroll
                for (int s = 0; s < 2; ++s)
                    hacc[s][nt] = __builtin_amdgcn_mfma_f32_16x16x32_bf16(
                        w1f, af[s][kt], hacc[s][nt], 0, 0, 0);
            }
        unsigned int wpk[2][4][2];
#pragma unroll
        for (int s = 0; s < 2; ++s)
#pragma unroll
            for (int t = 0; t < 4; ++t) {
                f32x4 hv = hacc[s][t];
#pragma unroll
                for (int r = 0; r < 4; ++r) hv[r] = gelu_f(hv[r]);
                wpk[s][t][0] = pk2(hv[0], hv[1]);
                wpk[s][t][1] = pk2(hv[2], hv[3]);
            }
#pragma unroll
        for (int kk = 0; kk < 2; ++kk) {
            int tl = kk * 2;
#pragma unroll
            for (int s = 0; s < 2; ++s) {
                unsigned int a0 = __shfl(wpk[s][tl][0],     srcA);
                unsigned int b0 = __shfl(wpk[s][tl + 1][0], srcA);
                unsigned int a1 = __shfl(wpk[s][tl][1],     srcA);
                unsigned int b1v = __shfl(wpk[s][tl + 1][1], srcA);
                unsigned int a2 = __shfl(wpk[s][tl][0],     srcB);
                unsigned int b2v = __shfl(wpk[s][tl + 1][0], srcB);
                unsigned int a3 = __shfl(wpk[s][tl][1],     srcB);
                unsigned int b3v = __shfl(wpk[s][tl + 1][1], srcB);
                u32x4 uu = { hiT ? b0 : a0, hiT ? b1v : a1, hiT ? b2v : a2, hiT ? b3v : a3 };
                bf16x8 pf = __builtin_bit_cast(bf16x8, uu);
#pragma unroll
                for (int nt2 = 0; nt2 < 8; ++nt2) {
                    int row2 = nt2 * 16 + la;
                    bf16x8 w2f = *reinterpret_cast<const bf16x8*>(
                        L2 + row2 * 128 + ((kk * 64 + lb * 16) ^ ((row2 & 7) << 4)));
                    acc[s][nt2] = __builtin_amdgcn_mfma_f32_16x16x32_bf16(
                        w2f, pf, acc[s][nt2], 0, 0, 0);
                }
            }
        }
        __syncthreads();
    }

    // ---- epilogue: + y residual (bf16) -> f32 out ----
#pragma unroll
    for (int s = 0; s < 2; ++s) {
        long m = m0 + s * 16 + la;
        const bf16_t* yrow = y + m * C_;
        float* orow = out + m * C_;
#pragma unroll
        for (int nt2 = 0; nt2 < 8; ++nt2) {
            int n2 = nt2 * 16 + lb * 4;
            bf16x4 rb = *reinterpret_cast<const bf16x4*>(yrow + n2);
            f32x4 val = acc[s][nt2];
#pragma unroll
            for (int r = 0; r < 4; ++r) val[r] += (float)rb[r];
            *reinterpret_cast<f32x4*>(orow + n2) = val;
        }
    }
}

// ---------------------------------------------------------------------------
extern "C" void kernel_launch(void* const* d_in, const int* in_sizes, int n_in,
                              void* d_out, int out_size, void* d_ws, size_t ws_size,
                              hipStream_t stream)
{
    (void)in_sizes; (void)n_in; (void)out_size;

    const float* x      = (const float*)d_in[0];
    const float* n1g    = (const float*)d_in[1];
    const float* n1b    = (const float*)d_in[2];
    const float* qkv_w  = (const float*)d_in[3];
    const float* qkv_b  = (const float*)d_in[4];
    const float* proj_w = (const float*)d_in[5];
    const float* proj_b = (const float*)d_in[6];
    const float* rpb    = (const float*)d_in[7];
    const float* n2g    = (const float*)d_in[8];
    const float* n2b    = (const float*)d_in[9];
    const float* fc1_w  = (const float*)d_in[10];
    const float* fc1_b  = (const float*)d_in[11];
    const float* fc2_w  = (const float*)d_in[12];
    const float* fc2_b  = (const float*)d_in[13];

    char* ws = (char*)d_ws;

    const size_t yb_sz = (size_t)M_ * 128 * 2;               // 51,380,224 (bf16 y)
    const size_t w_sz  = (size_t)(128 * 384 + 128 * 128 + 128 * 512 + 512 * 128) * 2;
    const size_t need  = yb_sz + w_sz;                       // ~51.8 MB

    if (need > ws_size) {
        sentinel_kernel<<<1, 256, 0, stream>>>((float*)d_out);
        return;
    }

    bf16_t* yb      = (bf16_t*)ws;
    bf16_t* qkv_wt  = (bf16_t*)(ws + yb_sz);
    bf16_t* proj_wt = qkv_wt + 128 * 384;
    bf16_t* fc1_wt  = proj_wt + 128 * 128;
    bf16_t* fc2_wt  = fc1_wt + 128 * 512;

    transpose_w<<<(128 * 384 + 255) / 256, 256, 0, stream>>>(qkv_w, qkv_wt, 128, 384);
    transpose_w<<<(128 * 128 + 255) / 256, 256, 0, stream>>>(proj_w, proj_wt, 128, 128);
    transpose_w<<<(128 * 512 + 255) / 256, 256, 0, stream>>>(fc1_w, fc1_wt, 128, 512);
    transpose_w<<<(512 * 128 + 255) / 256, 256, 0, stream>>>(fc2_w, fc2_wt, 512, 128);

    // LN1 + qkv + attention + proj + window-reverse + residual -> bf16 y
    swin_fused<<<NWIN, 256, 0, stream>>>(x, n1g, n1b, qkv_wt, qkv_b, rpb,
                                         proj_wt, proj_b, yb);
    // LN2 + fc1 + GELU + fc2 + residual -> f32 d_out
    mlp_fused<<<M_ / 512, 1024, 0, stream>>>(
        yb, n2g, n2b, fc1_wt, fc1_b, fc2_wt, fc2_b, (float*)d_out);
}

// Round 21
// 382.571 us; speedup vs baseline: 1.2773x; 1.0490x over previous
//
#include <hip/hip_runtime.h>
#include <hip/hip_bf16.h>
#include <math.h>

typedef __bf16 bf16x8 __attribute__((ext_vector_type(8)));
typedef __bf16 bf16x4 __attribute__((ext_vector_type(4)));
typedef float  f32x4  __attribute__((ext_vector_type(4)));
typedef unsigned int u32x4 __attribute__((ext_vector_type(4)));
typedef __hip_bfloat16 bf16_t;

static constexpr int C_    = 128;
static constexpr int L_    = 56 * 56;        // tokens per image
static constexpr int M_    = 64 * L_;        // 200704 total tokens
static constexpr int NWIN  = 64 * 64;        // 4096 windows

// map windowed token index tw -> unwindowed token index (shift+window bijection)
__device__ inline long win_to_tok(int tw)
{
    int win = tw / 49, n = tw % 49;
    int bb  = win >> 6, wi = win & 63;
    int wh  = wi >> 3, wwp = wi & 7;
    int hs  = wh * 7 + n / 7;
    int wsv = wwp * 7 + n % 7;
    int hh  = (hs + 3) % 56;          // un-shift
    int ww  = (wsv + 3) % 56;
    return (long)bb * L_ + hh * 56 + ww;
}

__device__ inline unsigned int pk2(float lo, float hi)
{
    unsigned short a = __builtin_bit_cast(unsigned short, (__bf16)lo);
    unsigned short b = __builtin_bit_cast(unsigned short, (__bf16)hi);
    return (unsigned int)a | ((unsigned int)b << 16);
}

// tanh-form GELU: ~8 VALU ops, |err| <= ~3e-3 (threshold is 0.11).
__device__ inline float gelu_f(float x)
{
    float u = 0.7978845608f * x * (1.f + 0.044715f * x * x);
    float e = __expf(2.f * fminf(u, 15.f));
    return x * e * __builtin_amdgcn_rcpf(e + 1.f);
}

__global__ void sentinel_kernel(float* o) { o[threadIdx.x] = 1e9f; }

// ---------------------------------------------------------------------------
__global__ void transpose_w(const float* __restrict__ w, bf16_t* __restrict__ wt,
                            int K, int N)
{
    int i = blockIdx.x * 256 + threadIdx.x;
    if (i >= K * N) return;
    int k = i / N, n = i % N;
    wt[(long)n * K + k] = __float2bfloat16(w[i]);
}

// ---------------------------------------------------------------------------
// Fully fused Swin attention half (R15 version, verbatim — proven 258 us):
// LN1 + qkv + windowed attention + proj + window-reverse + x residual,
// one block per window (4 waves = 4 heads).
// LDS: xn[64][256B] (aliased by attw[49][152] after phase 2) |
//      qk[64][512B] XOR-swizzled | vT[128][56] bf16 (pads zeroed).
// ---------------------------------------------------------------------------
__global__ __launch_bounds__(256) void swin_fused(const float* __restrict__ x,
                                                  const float* __restrict__ lng,
                                                  const float* __restrict__ lnb,
                                                  const bf16_t* __restrict__ qkvwt,
                                                  const float*  __restrict__ qkvb,
                                                  const float*  __restrict__ rpb,
                                                  const bf16_t* __restrict__ projwt,
                                                  const float*  __restrict__ projb,
                                                  bf16_t* __restrict__ y)
{
    __shared__ char smem[16384 + 32768 + 14336];   // 63.5 KB
    char*   xnb = smem;                    // phase 1-2: LN1'd x; phase 3+: attw
    char*   qkb = smem + 16384;            // [64 rows][512 B], swizzled
    __bf16* vtb = (__bf16*)(smem + 49152); // [128][56]

    int win  = blockIdx.x;
    int tid  = threadIdx.x;
    int wave = tid >> 6;
    int lane = tid & 63;
    int la = lane & 15, lb = lane >> 4;

    // zero vT pad keys 49..55 (NaN safety: P[pad]=0 x V[pad] must be 0)
    for (int i = tid; i < 128 * 7; i += 256)
        vtb[(i / 7) * 56 + 49 + i % 7] = (__bf16)0.f;

    // ---- phase 1: LN1 of window tokens -> xn ----
    {
        int row = wave * 16 + la;
        int tw  = win * 49 + row;
        if (tw > M_ - 1) tw = M_ - 1;      // rows >=49 duplicate data, discarded
        long src = win_to_tok(tw);
        const float* xr = x + src * C_;
        float vals[4][8];
        float sm = 0.f, qs = 0.f;
#pragma unroll
        for (int kt = 0; kt < 4; ++kt) {
            f32x4 u0 = *reinterpret_cast<const f32x4*>(xr + kt * 32 + lb * 8);
            f32x4 u1 = *reinterpret_cast<const f32x4*>(xr + kt * 32 + lb * 8 + 4);
#pragma unroll
            for (int j = 0; j < 4; ++j) { vals[kt][j] = u0[j]; vals[kt][4 + j] = u1[j]; }
#pragma unroll
            for (int j = 0; j < 8; ++j) { sm += vals[kt][j]; qs += vals[kt][j] * vals[kt][j]; }
        }
        sm += __shfl_xor(sm, 16); sm += __shfl_xor(sm, 32);
        qs += __shfl_xor(qs, 16); qs += __shfl_xor(qs, 32);
        float mean = sm * (1.f / 128.f);
        float rstd = rsqrtf(qs * (1.f / 128.f) - mean * mean + 1e-5f);
#pragma unroll
        for (int kt = 0; kt < 4; ++kt) {
            bf16x8 v8;
#pragma unroll
            for (int j = 0; j < 8; ++j) {
                int col = kt * 32 + lb * 8 + j;
                v8[j] = (__bf16)((vals[kt][j] - mean) * rstd * lng[col] + lnb[col]);
            }
            int colb = kt * 64 + lb * 16;
            *reinterpret_cast<bf16x8*>(xnb + row * 256 + (colb ^ ((row & 7) << 4))) = v8;
        }
    }
    __syncthreads();

    // ---- phase 2: qkv, wave = 64 rows x 96 cols; outputs -> LDS ----
    {
        int c0 = wave * 96;
        f32x4 acc[4][6];
#pragma unroll
        for (int nt = 0; nt < 6; ++nt) {
            float bv = qkvb[c0 + nt * 16 + la];
#pragma unroll
            for (int s = 0; s < 4; ++s) acc[s][nt] = (f32x4){bv, bv, bv, bv};
        }
#pragma unroll
        for (int kt = 0; kt < 4; ++kt) {
            bf16x8 ar[4];
#pragma unroll
            for (int s = 0; s < 4; ++s) {
                int row = s * 16 + la;
                ar[s] = *reinterpret_cast<const bf16x8*>(
                    xnb + row * 256 + ((kt * 64 + lb * 16) ^ ((row & 7) << 4)));
            }
#pragma unroll
            for (int nt = 0; nt < 6; ++nt) {
                bf16x8 br = *reinterpret_cast<const bf16x8*>(
                    qkvwt + (long)(c0 + nt * 16 + la) * 128 + kt * 32 + lb * 8);
#pragma unroll
                for (int s = 0; s < 4; ++s)
                    acc[s][nt] = __builtin_amdgcn_mfma_f32_16x16x32_bf16(
                        ar[s], br, acc[s][nt], 0, 0, 0);
            }
        }
        // epilogue -> LDS (q,k swizzled rows; v transposed, key<49 only)
#pragma unroll
        for (int s = 0; s < 4; ++s) {
#pragma unroll
            for (int r = 0; r < 4; ++r) {
                int row = s * 16 + lb * 4 + r;     // window-local token = key
#pragma unroll
                for (int nt = 0; nt < 6; ++nt) {
                    int col = c0 + nt * 16 + la;
                    float v = acc[s][nt][r];
                    if (col < 256) {
                        *reinterpret_cast<__bf16*>(
                            qkb + row * 512 + ((col * 2) ^ ((row & 7) << 4))) = (__bf16)v;
                    } else if (row < 49) {
                        vtb[(col - 256) * 56 + row] = (__bf16)v;
                    }
                }
            }
        }
    }
    __syncthreads();

    // ---- phase 3: attention (wave = head h) ----
    int h = wave;
    bf16x8 kf[4], qf[4];
#pragma unroll
    for (int t = 0; t < 4; ++t) {
        int row = t * 16 + la;
        kf[t] = *reinterpret_cast<const bf16x8*>(
            qkb + row * 512 + ((256 + h * 64 + lb * 16) ^ ((row & 7) << 4)));
        qf[t] = *reinterpret_cast<const bf16x8*>(
            qkb + row * 512 + ((      h * 64 + lb * 16) ^ ((row & 7) << 4)));
    }

    f32x4 S[4][4];
#pragma unroll
    for (int qt = 0; qt < 4; ++qt)
#pragma unroll
        for (int kt = 0; kt < 4; ++kt)
            S[qt][kt] = __builtin_amdgcn_mfma_f32_16x16x32_bf16(
                kf[kt], qf[qt], (f32x4){0.f, 0.f, 0.f, 0.f}, 0, 0, 0);

    const float scale = 0.17677669529663687f;   // 1/sqrt(32)
    int wi  = win & 63;
    int wh  = wi >> 3, wwp = wi & 7;
    bool edge = (wh == 7) || (wwp == 7);

    int i1[4], j1[4], r1[4], c1[4];
#pragma unroll
    for (int qt = 0; qt < 4; ++qt) {
        int q  = qt * 16 + la;
        int qc = q < 49 ? q : 48;
        i1[qt] = qc / 7; j1[qt] = qc - 7 * i1[qt];
        r1[qt] = (wh  < 7) ? 0 : ((i1[qt] < 4) ? 1 : 2);
        c1[qt] = (wwp < 7) ? 0 : ((j1[qt] < 4) ? 1 : 2);
    }

#pragma unroll
    for (int kt = 0; kt < 4; ++kt) {
#pragma unroll
        for (int r = 0; r < 4; ++r) {
            if (kt == 3 && r > 0) {
#pragma unroll
                for (int qt = 0; qt < 4; ++qt) S[qt][kt][r] = -1e30f;
                continue;
            }
            int key = kt * 16 + lb * 4 + r;
            int kc  = key < 49 ? key : 48;
            int i2  = kc / 7, j2 = kc - 7 * i2;
            int r2  = (wh  < 7) ? 0 : ((i2 < 4) ? 1 : 2);
            int c2  = (wwp < 7) ? 0 : ((j2 < 4) ? 1 : 2);
#pragma unroll
            for (int qt = 0; qt < 4; ++qt) {
                float bv  = rpb[(((i1[qt] - i2 + 6) * 13 + (j1[qt] - j2 + 6)) << 2) + h];
                float val = S[qt][kt][r] * scale + bv;
                if (edge && ((r1[qt] != r2) | (c1[qt] != c2))) val -= 100.f;
                if (kt == 3 && lb > 0) val = -1e30f;
                S[qt][kt][r] = val;
            }
        }
    }

    float inv[4];
#pragma unroll
    for (int qt = 0; qt < 4; ++qt) {
        float mx = -3e38f;
#pragma unroll
        for (int kt = 0; kt < 4; ++kt)
#pragma unroll
            for (int r = 0; r < 4; ++r) mx = fmaxf(mx, S[qt][kt][r]);
        mx = fmaxf(mx, __shfl_xor(mx, 16));
        mx = fmaxf(mx, __shfl_xor(mx, 32));
        float sm = 0.f;
#pragma unroll
        for (int kt = 0; kt < 4; ++kt)
#pragma unroll
            for (int r = 0; r < 4; ++r) {
                float e = __expf(S[qt][kt][r] - mx);
                S[qt][kt][r] = e;
                sm += e;
            }
        sm += __shfl_xor(sm, 16);
        sm += __shfl_xor(sm, 32);
        inv[qt] = 1.f / sm;
    }

    unsigned int w_[4][4][2];
#pragma unroll
    for (int qt = 0; qt < 4; ++qt)
#pragma unroll
        for (int t = 0; t < 4; ++t) {
            w_[qt][t][0] = pk2(S[qt][t][0], S[qt][t][1]);
            w_[qt][t][1] = pk2(S[qt][t][2], S[qt][t][3]);
        }

    int srcA = la + (((2 * lb)     & 3) << 4);
    int srcB = la + (((2 * lb + 1) & 3) << 4);
    bool hiT = (lb >> 1) & 1;

    f32x4 O[2][4];
#pragma unroll
    for (int dt = 0; dt < 2; ++dt)
#pragma unroll
        for (int qt = 0; qt < 4; ++qt) O[dt][qt] = (f32x4){0.f, 0.f, 0.f, 0.f};

#pragma unroll
    for (int kk = 0; kk < 2; ++kk) {
        bf16x8 vf[2];
#pragma unroll
        for (int dt = 0; dt < 2; ++dt)
            vf[dt] = *reinterpret_cast<const bf16x8*>(
                vtb + (h * 32 + dt * 16 + la) * 56 + kk * 32 + lb * 8);
        int tl = kk * 2;
#pragma unroll
        for (int qt = 0; qt < 4; ++qt) {
            unsigned int a0 = __shfl(w_[qt][tl][0],     srcA);
            unsigned int b0 = __shfl(w_[qt][tl + 1][0], srcA);
            unsigned int a1 = __shfl(w_[qt][tl][1],     srcA);
            unsigned int b1 = __shfl(w_[qt][tl + 1][1], srcA);
            unsigned int a2 = __shfl(w_[qt][tl][0],     srcB);
            unsigned int b2 = __shfl(w_[qt][tl + 1][0], srcB);
            unsigned int a3 = __shfl(w_[qt][tl][1],     srcB);
            unsigned int b3 = __shfl(w_[qt][tl + 1][1], srcB);
            u32x4 uu = { hiT ? b0 : a0, hiT ? b1 : a1, hiT ? b2 : a2, hiT ? b3 : a3 };
            bf16x8 pf = __builtin_bit_cast(bf16x8, uu);
#pragma unroll
            for (int dt = 0; dt < 2; ++dt)
                O[dt][qt] = __builtin_amdgcn_mfma_f32_16x16x32_bf16(vf[dt], pf, O[dt][qt], 0, 0, 0);
        }
    }

    // ---- normalized O -> attw (aliases xn; xn dead since phase-2 barrier) ----
    __bf16 (*attw)[152] = (__bf16(*)[152])xnb;
#pragma unroll
    for (int qt = 0; qt < 4; ++qt) {
        int q = qt * 16 + la;
        if (q < 49) {
            float iv = inv[qt];
#pragma unroll
            for (int dt = 0; dt < 2; ++dt) {
                unsigned int s0 = pk2(O[dt][qt][0] * iv, O[dt][qt][1] * iv);
                unsigned int s1 = pk2(O[dt][qt][2] * iv, O[dt][qt][3] * iv);
                uint2 st = {s0, s1};
                *reinterpret_cast<uint2*>(&attw[q][h * 32 + dt * 16 + lb * 4]) = st;
            }
        }
    }
    __syncthreads();

    // ---- phase 4: proj, wave h computes C[q=0..63][n=h*32..h*32+31] ----
    int n0 = h * 32;
    f32x4 pacc[4][2];
#pragma unroll
    for (int nt = 0; nt < 2; ++nt) {
        float bv = projb[n0 + nt * 16 + la];
#pragma unroll
        for (int s = 0; s < 4; ++s) pacc[s][nt] = (f32x4){bv, bv, bv, bv};
    }
#pragma unroll
    for (int kt = 0; kt < 4; ++kt) {
        bf16x8 ar[4];
#pragma unroll
        for (int s = 0; s < 4; ++s)
            ar[s] = *reinterpret_cast<const bf16x8*>(&attw[s * 16 + la][kt * 32 + lb * 8]);
#pragma unroll
        for (int nt = 0; nt < 2; ++nt) {
            bf16x8 br = *reinterpret_cast<const bf16x8*>(
                projwt + (long)(n0 + nt * 16 + la) * 128 + kt * 32 + lb * 8);
#pragma unroll
            for (int s = 0; s < 4; ++s)
                pacc[s][nt] = __builtin_amdgcn_mfma_f32_16x16x32_bf16(
                    ar[s], br, pacc[s][nt], 0, 0, 0);
        }
    }

    // ---- epilogue: window-reverse + unshift + x residual -> bf16 y ----
#pragma unroll
    for (int s = 0; s < 4; ++s) {
#pragma unroll
        for (int r = 0; r < 4; ++r) {
            int q = s * 16 + lb * 4 + r;
            if (q < 49) {
                long to = win_to_tok(win * 49 + q);
#pragma unroll
                for (int nt = 0; nt < 2; ++nt) {
                    int col = n0 + nt * 16 + la;
                    y[to * C_ + col] =
                        __float2bfloat16(pacc[s][nt][r] + x[to * C_ + col]);
                }
            }
        }
    }
}

// ---------------------------------------------------------------------------
// Fused MLP v8 (R15 version, verbatim — proven): bf16 y, 512-thread blocks,
// single 32 KB LDS weight buffer, XOR-swizzled rows. out (f32) written once.
// ---------------------------------------------------------------------------
__global__ __launch_bounds__(512, 4) void mlp_fused(const bf16_t* __restrict__ y,
                                                    const float* __restrict__ g,
                                                    const float* __restrict__ b,
                                                    const bf16_t* __restrict__ w1t,
                                                    const float* __restrict__ b1,
                                                    const bf16_t* __restrict__ w2t,
                                                    const float* __restrict__ b2,
                                                    float* __restrict__ out)
{
    __shared__ uint4 ldsq[2048];             // 32 KB: [W1c 16KB | W2c 16KB]
    int tid  = threadIdx.x;
    int lane = tid & 63;
    int la = lane & 15, lb = lane >> 4;
    int m0 = (blockIdx.x * 8 + (tid >> 6)) * 32;

    auto stage = [&](int c) {
        char* d1 = (char*)&ldsq[0];
        const char* s1 = (const char*)w1t + (size_t)c * 16384;
#pragma unroll
        for (int i = 0; i < 2; ++i) {
            int idx = i * 512 + tid;             // 0..1023, 16B units
            int row = idx >> 4, colb = (idx & 15) * 16;
            uint4 v = *reinterpret_cast<const uint4*>(s1 + idx * 16);
            *reinterpret_cast<uint4*>(d1 + row * 256 + (colb ^ ((row & 7) << 4))) = v;
        }
        char* d2 = (char*)&ldsq[1024];
        const char* s2 = (const char*)w2t + (size_t)c * 128;
#pragma unroll
        for (int i = 0; i < 2; ++i) {
            int idx = i * 512 + tid;             // 0..1023
            int row = idx >> 3, colb = (idx & 7) * 16;
            uint4 v = *reinterpret_cast<const uint4*>(s2 + (size_t)row * 1024 + colb);
            *reinterpret_cast<uint4*>(d2 + row * 128 + (colb ^ ((row & 7) << 4))) = v;
        }
    };

    // ---- LN2 -> fragments for 2 row-subtiles ----
    bf16x8 af[2][4];
#pragma unroll
    for (int s = 0; s < 2; ++s) {
        const bf16_t* yr = y + (long)(m0 + s * 16 + la) * C_;
        float vals[4][8];
        float sm = 0.f, qs = 0.f;
#pragma unroll
        for (int kt = 0; kt < 4; ++kt) {
            bf16x8 v8 = *reinterpret_cast<const bf16x8*>(yr + kt * 32 + lb * 8);
#pragma unroll
            for (int j = 0; j < 8; ++j) {
                float v = (float)v8[j];
                vals[kt][j] = v; sm += v; qs += v * v;
            }
        }
        sm += __shfl_xor(sm, 16); sm += __shfl_xor(sm, 32);
        qs += __shfl_xor(qs, 16); qs += __shfl_xor(qs, 32);
        float mean = sm * (1.f / 128.f);
        float rstd = rsqrtf(qs * (1.f / 128.f) - mean * mean + 1e-5f);
#pragma unroll
        for (int kt = 0; kt < 4; ++kt)
#pragma unroll
            for (int j = 0; j < 8; ++j) {
                int col = kt * 32 + lb * 8 + j;
                af[s][kt][j] = (__bf16)((vals[kt][j] - mean) * rstd * g[col] + b[col]);
            }
    }

    f32x4 acc[2][8];
#pragma unroll
    for (int nt2 = 0; nt2 < 8; ++nt2) {
        f32x4 bv = *reinterpret_cast<const f32x4*>(b2 + nt2 * 16 + lb * 4);
#pragma unroll
        for (int s = 0; s < 2; ++s) acc[s][nt2] = bv;
    }

    int srcA = la + (((2 * lb)     & 3) << 4);
    int srcB = la + (((2 * lb + 1) & 3) << 4);
    bool hiT = (lb >> 1) & 1;

    for (int c = 0; c < 8; ++c) {
        stage(c);
        __syncthreads();

        const char* L1 = (const char*)&ldsq[0];
        const char* L2 = (const char*)&ldsq[1024];

        f32x4 hacc[2][4];
#pragma unroll
        for (int nt = 0; nt < 4; ++nt) {
            f32x4 bv = *reinterpret_cast<const f32x4*>(b1 + c * 64 + nt * 16 + lb * 4);
#pragma unroll
            for (int s = 0; s < 2; ++s) hacc[s][nt] = bv;
        }
#pragma unroll
        for (int kt = 0; kt < 4; ++kt)
#pragma unroll
            for (int nt = 0; nt < 4; ++nt) {
                int row = nt * 16 + la;
                bf16x8 w1f = *reinterpret_cast<const bf16x8*>(
                    L1 + row * 256 + ((kt * 64 + lb * 16) ^ ((row & 7) << 4)));
#pragma unroll
                for (int s = 0; s < 2; ++s)
                    hacc[s][nt] = __builtin_amdgcn_mfma_f32_16x16x32_bf16(
                        w1f, af[s][kt], hacc[s][nt], 0, 0, 0);
            }
        unsigned int wpk[2][4][2];
#pragma unroll
        for (int s = 0; s < 2; ++s)
#pragma unroll
            for (int t = 0; t < 4; ++t) {
                f32x4 hv = hacc[s][t];
#pragma unroll
                for (int r = 0; r < 4; ++r) hv[r] = gelu_f(hv[r]);
                wpk[s][t][0] = pk2(hv[0], hv[1]);
                wpk[s][t][1] = pk2(hv[2], hv[3]);
            }
#pragma unroll
        for (int kk = 0; kk < 2; ++kk) {
            int tl = kk * 2;
#pragma unroll
            for (int s = 0; s < 2; ++s) {
                unsigned int a0 = __shfl(wpk[s][tl][0],     srcA);
                unsigned int b0 = __shfl(wpk[s][tl + 1][0], srcA);
                unsigned int a1 = __shfl(wpk[s][tl][1],     srcA);
                unsigned int b1v = __shfl(wpk[s][tl + 1][1], srcA);
                unsigned int a2 = __shfl(wpk[s][tl][0],     srcB);
                unsigned int b2v = __shfl(wpk[s][tl + 1][0], srcB);
                unsigned int a3 = __shfl(wpk[s][tl][1],     srcB);
                unsigned int b3v = __shfl(wpk[s][tl + 1][1], srcB);
                u32x4 uu = { hiT ? b0 : a0, hiT ? b1v : a1, hiT ? b2v : a2, hiT ? b3v : a3 };
                bf16x8 pf = __builtin_bit_cast(bf16x8, uu);
#pragma unroll
                for (int nt2 = 0; nt2 < 8; ++nt2) {
                    int row2 = nt2 * 16 + la;
                    bf16x8 w2f = *reinterpret_cast<const bf16x8*>(
                        L2 + row2 * 128 + ((kk * 64 + lb * 16) ^ ((row2 & 7) << 4)));
                    acc[s][nt2] = __builtin_amdgcn_mfma_f32_16x16x32_bf16(
                        w2f, pf, acc[s][nt2], 0, 0, 0);
                }
            }
        }
        __syncthreads();
    }

    // ---- epilogue: + y residual (bf16) -> f32 out ----
#pragma unroll
    for (int s = 0; s < 2; ++s) {
        long m = m0 + s * 16 + la;
        const bf16_t* yrow = y + m * C_;
        float* orow = out + m * C_;
#pragma unroll
        for (int nt2 = 0; nt2 < 8; ++nt2) {
            int n2 = nt2 * 16 + lb * 4;
            bf16x4 rb = *reinterpret_cast<const bf16x4*>(yrow + n2);
            f32x4 val = acc[s][nt2];
#pragma unroll
            for (int r = 0; r < 4; ++r) val[r] += (float)rb[r];
            *reinterpret_cast<f32x4*>(orow + n2) = val;
        }
    }
}

// ---------------------------------------------------------------------------
extern "C" void kernel_launch(void* const* d_in, const int* in_sizes, int n_in,
                              void* d_out, int out_size, void* d_ws, size_t ws_size,
                              hipStream_t stream)
{
    (void)in_sizes; (void)n_in; (void)out_size;

    const float* x      = (const float*)d_in[0];
    const float* n1g    = (const float*)d_in[1];
    const float* n1b    = (const float*)d_in[2];
    const float* qkv_w  = (const float*)d_in[3];
    const float* qkv_b  = (const float*)d_in[4];
    const float* proj_w = (const float*)d_in[5];
    const float* proj_b = (const float*)d_in[6];
    const float* rpb    = (const float*)d_in[7];
    const float* n2g    = (const float*)d_in[8];
    const float* n2b    = (const float*)d_in[9];
    const float* fc1_w  = (const float*)d_in[10];
    const float* fc1_b  = (const float*)d_in[11];
    const float* fc2_w  = (const float*)d_in[12];
    const float* fc2_b  = (const float*)d_in[13];

    char* ws = (char*)d_ws;

    const size_t yb_sz = (size_t)M_ * 128 * 2;               // 51,380,224 (bf16 y)
    const size_t w_sz  = (size_t)(128 * 384 + 128 * 128 + 128 * 512 + 512 * 128) * 2;
    const size_t need  = yb_sz + w_sz;                       // ~51.8 MB

    if (need > ws_size) {
        sentinel_kernel<<<1, 256, 0, stream>>>((float*)d_out);
        return;
    }

    bf16_t* yb      = (bf16_t*)ws;
    bf16_t* qkv_wt  = (bf16_t*)(ws + yb_sz);
    bf16_t* proj_wt = qkv_wt + 128 * 384;
    bf16_t* fc1_wt  = proj_wt + 128 * 128;
    bf16_t* fc2_wt  = fc1_wt + 128 * 512;

    transpose_w<<<(128 * 384 + 255) / 256, 256, 0, stream>>>(qkv_w, qkv_wt, 128, 384);
    transpose_w<<<(128 * 128 + 255) / 256, 256, 0, stream>>>(proj_w, proj_wt, 128, 128);
    transpose_w<<<(128 * 512 + 255) / 256, 256, 0, stream>>>(fc1_w, fc1_wt, 128, 512);
    transpose_w<<<(512 * 128 + 255) / 256, 256, 0, stream>>>(fc2_w, fc2_wt, 512, 128);

    // LN1 + qkv + attention + proj + window-reverse + residual -> bf16 y
    swin_fused<<<NWIN, 256, 0, stream>>>(x, n1g, n1b, qkv_wt, qkv_b, rpb,
                                         proj_wt, proj_b, yb);
    // LN2 + fc1 + GELU + fc2 + residual -> f32 d_out
    mlp_fused<<<M_ / 256, 512, 0, stream>>>(
        yb, n2g, n2b, fc1_wt, fc1_b, fc2_wt, fc2_b, (float*)d_out);
}

// Round 22
// 354.592 us; speedup vs baseline: 1.3780x; 1.0789x over previous
//
#include <hip/hip_runtime.h>
#include <hip/hip_bf16.h>
#include <math.h>

typedef __bf16 bf16x8 __attribute__((ext_vector_type(8)));
typedef __bf16 bf16x4 __attribute__((ext_vector_type(4)));
typedef float  f32x4  __attribute__((ext_vector_type(4)));
typedef unsigned int u32x4 __attribute__((ext_vector_type(4)));
typedef __hip_bfloat16 bf16_t;

static constexpr int C_    = 128;
static constexpr int L_    = 56 * 56;        // tokens per image
static constexpr int M_    = 64 * L_;        // 200704 total tokens
static constexpr int NWIN  = 64 * 64;        // 4096 windows

// map windowed token index tw -> unwindowed token index (shift+window bijection)
__device__ inline long win_to_tok(int tw)
{
    int win = tw / 49, n = tw % 49;
    int bb  = win >> 6, wi = win & 63;
    int wh  = wi >> 3, wwp = wi & 7;
    int hs  = wh * 7 + n / 7;
    int wsv = wwp * 7 + n % 7;
    int hh  = (hs + 3) % 56;          // un-shift
    int ww  = (wsv + 3) % 56;
    return (long)bb * L_ + hh * 56 + ww;
}

__device__ inline unsigned int pk2(float lo, float hi)
{
    unsigned short a = __builtin_bit_cast(unsigned short, (__bf16)lo);
    unsigned short b = __builtin_bit_cast(unsigned short, (__bf16)hi);
    return (unsigned int)a | ((unsigned int)b << 16);
}

// tanh-form GELU: ~8 VALU ops, |err| <= ~3e-3 (threshold is 0.11).
__device__ inline float gelu_f(float x)
{
    float u = 0.7978845608f * x * (1.f + 0.044715f * x * x);
    float e = __expf(2.f * fminf(u, 15.f));
    return x * e * __builtin_amdgcn_rcpf(e + 1.f);
}

__global__ void sentinel_kernel(float* o) { o[threadIdx.x] = 1e9f; }

// ---------------------------------------------------------------------------
__global__ void transpose_w(const float* __restrict__ w, bf16_t* __restrict__ wt,
                            int K, int N)
{
    int i = blockIdx.x * 256 + threadIdx.x;
    if (i >= K * N) return;
    int k = i / N, n = i % N;
    wt[(long)n * K + k] = __float2bfloat16(w[i]);
}

// ---------------------------------------------------------------------------
// Precompute bias+mask table: tbl[type][h][q][key64] f32.
// type = (wh==7)*2 + (wwp==7). keys >=49 get -1e30 (pad masking folded in).
// ---------------------------------------------------------------------------
__global__ void build_bias_tbl(const float* __restrict__ rpb, float* __restrict__ tbl)
{
    int idx = blockIdx.x * 256 + threadIdx.x;
    if (idx >= 4 * 4 * 49 * 64) return;
    int key  = idx & 63;
    int q    = (idx >> 6) % 49;
    int h    = (idx / (64 * 49)) & 3;
    int type = idx / (64 * 49 * 4);
    float v = -1e30f;
    if (key < 49) {
        int i1 = q / 7, j1 = q % 7, i2 = key / 7, j2 = key % 7;
        float bias = rpb[((i1 - i2 + 6) * 13 + (j1 - j2 + 6)) * 4 + h];
        int r1 = (type & 2) ? (i1 < 4 ? 1 : 2) : 0;
        int r2 = (type & 2) ? (i2 < 4 ? 1 : 2) : 0;
        int c1 = (type & 1) ? (j1 < 4 ? 1 : 2) : 0;
        int c2 = (type & 1) ? (j2 < 4 ? 1 : 2) : 0;
        v = bias + (((r1 != r2) | (c1 != c2)) ? -100.f : 0.f);
    }
    tbl[idx] = v;
}

// ---------------------------------------------------------------------------
// Fully fused Swin attention half (R15 structure; bias/mask via table):
// LN1 + qkv + windowed attention + proj + window-reverse + x residual,
// one block per window (4 waves = 4 heads).
// LDS: xn[64][256B] (aliased by attw[49][152] after phase 2) |
//      qk[64][512B] XOR-swizzled | vT[128][56] bf16 (pads zeroed).
// ---------------------------------------------------------------------------
__global__ __launch_bounds__(256) void swin_fused(const float* __restrict__ x,
                                                  const float* __restrict__ lng,
                                                  const float* __restrict__ lnb,
                                                  const bf16_t* __restrict__ qkvwt,
                                                  const float*  __restrict__ qkvb,
                                                  const float*  __restrict__ btbl,
                                                  const bf16_t* __restrict__ projwt,
                                                  const float*  __restrict__ projb,
                                                  bf16_t* __restrict__ y)
{
    __shared__ char smem[16384 + 32768 + 14336];   // 63.5 KB
    char*   xnb = smem;                    // phase 1-2: LN1'd x; phase 3+: attw
    char*   qkb = smem + 16384;            // [64 rows][512 B], swizzled
    __bf16* vtb = (__bf16*)(smem + 49152); // [128][56]

    int win  = blockIdx.x;
    int tid  = threadIdx.x;
    int wave = tid >> 6;
    int lane = tid & 63;
    int la = lane & 15, lb = lane >> 4;

    // zero vT pad keys 49..55 (NaN safety: P[pad]=0 x V[pad] must be 0)
    for (int i = tid; i < 128 * 7; i += 256)
        vtb[(i / 7) * 56 + 49 + i % 7] = (__bf16)0.f;

    // ---- phase 1: LN1 of window tokens -> xn ----
    {
        int row = wave * 16 + la;
        int tw  = win * 49 + row;
        if (tw > M_ - 1) tw = M_ - 1;      // rows >=49 duplicate data, discarded
        long src = win_to_tok(tw);
        const float* xr = x + src * C_;
        float vals[4][8];
        float sm = 0.f, qs = 0.f;
#pragma unroll
        for (int kt = 0; kt < 4; ++kt) {
            f32x4 u0 = *reinterpret_cast<const f32x4*>(xr + kt * 32 + lb * 8);
            f32x4 u1 = *reinterpret_cast<const f32x4*>(xr + kt * 32 + lb * 8 + 4);
#pragma unroll
            for (int j = 0; j < 4; ++j) { vals[kt][j] = u0[j]; vals[kt][4 + j] = u1[j]; }
#pragma unroll
            for (int j = 0; j < 8; ++j) { sm += vals[kt][j]; qs += vals[kt][j] * vals[kt][j]; }
        }
        sm += __shfl_xor(sm, 16); sm += __shfl_xor(sm, 32);
        qs += __shfl_xor(qs, 16); qs += __shfl_xor(qs, 32);
        float mean = sm * (1.f / 128.f);
        float rstd = rsqrtf(qs * (1.f / 128.f) - mean * mean + 1e-5f);
#pragma unroll
        for (int kt = 0; kt < 4; ++kt) {
            bf16x8 v8;
#pragma unroll
            for (int j = 0; j < 8; ++j) {
                int col = kt * 32 + lb * 8 + j;
                v8[j] = (__bf16)((vals[kt][j] - mean) * rstd * lng[col] + lnb[col]);
            }
            int colb = kt * 64 + lb * 16;
            *reinterpret_cast<bf16x8*>(xnb + row * 256 + (colb ^ ((row & 7) << 4))) = v8;
        }
    }
    __syncthreads();

    // ---- phase 2: qkv, wave = 64 rows x 96 cols; outputs -> LDS ----
    {
        int c0 = wave * 96;
        f32x4 acc[4][6];
#pragma unroll
        for (int nt = 0; nt < 6; ++nt) {
            float bv = qkvb[c0 + nt * 16 + la];
#pragma unroll
            for (int s = 0; s < 4; ++s) acc[s][nt] = (f32x4){bv, bv, bv, bv};
        }
#pragma unroll
        for (int kt = 0; kt < 4; ++kt) {
            bf16x8 ar[4];
#pragma unroll
            for (int s = 0; s < 4; ++s) {
                int row = s * 16 + la;
                ar[s] = *reinterpret_cast<const bf16x8*>(
                    xnb + row * 256 + ((kt * 64 + lb * 16) ^ ((row & 7) << 4)));
            }
#pragma unroll
            for (int nt = 0; nt < 6; ++nt) {
                bf16x8 br = *reinterpret_cast<const bf16x8*>(
                    qkvwt + (long)(c0 + nt * 16 + la) * 128 + kt * 32 + lb * 8);
#pragma unroll
                for (int s = 0; s < 4; ++s)
                    acc[s][nt] = __builtin_amdgcn_mfma_f32_16x16x32_bf16(
                        ar[s], br, acc[s][nt], 0, 0, 0);
            }
        }
        // epilogue -> LDS (q,k swizzled rows; v transposed, key<49 only)
#pragma unroll
        for (int s = 0; s < 4; ++s) {
#pragma unroll
            for (int r = 0; r < 4; ++r) {
                int row = s * 16 + lb * 4 + r;     // window-local token = key
#pragma unroll
                for (int nt = 0; nt < 6; ++nt) {
                    int col = c0 + nt * 16 + la;
                    float v = acc[s][nt][r];
                    if (col < 256) {
                        *reinterpret_cast<__bf16*>(
                            qkb + row * 512 + ((col * 2) ^ ((row & 7) << 4))) = (__bf16)v;
                    } else if (row < 49) {
                        vtb[(col - 256) * 56 + row] = (__bf16)v;
                    }
                }
            }
        }
    }
    __syncthreads();

    // ---- phase 3: attention (wave = head h) ----
    int h = wave;
    bf16x8 kf[4], qf[4];
#pragma unroll
    for (int t = 0; t < 4; ++t) {
        int row = t * 16 + la;
        kf[t] = *reinterpret_cast<const bf16x8*>(
            qkb + row * 512 + ((256 + h * 64 + lb * 16) ^ ((row & 7) << 4)));
        qf[t] = *reinterpret_cast<const bf16x8*>(
            qkb + row * 512 + ((      h * 64 + lb * 16) ^ ((row & 7) << 4)));
    }

    f32x4 S[4][4];
#pragma unroll
    for (int qt = 0; qt < 4; ++qt)
#pragma unroll
        for (int kt = 0; kt < 4; ++kt)
            S[qt][kt] = __builtin_amdgcn_mfma_f32_16x16x32_bf16(
                kf[kt], qf[qt], (f32x4){0.f, 0.f, 0.f, 0.f}, 0, 0, 0);

    // ---- bias + mask via precomputed table ----
    const float scale = 0.17677669529663687f;   // 1/sqrt(32)
    {
        int wi   = win & 63;
        int wh   = wi >> 3, wwp = wi & 7;
        int type = ((wh == 7) ? 2 : 0) + ((wwp == 7) ? 1 : 0);
        const float* tb = btbl + (size_t)((type * 4 + h) * 49) * 64;
#pragma unroll
        for (int qt = 0; qt < 4; ++qt) {
            int q  = qt * 16 + la;
            int qc = q < 49 ? q : 48;
            const float* tq = tb + qc * 64 + lb * 4;
#pragma unroll
            for (int kt = 0; kt < 4; ++kt) {
                f32x4 bv = *reinterpret_cast<const f32x4*>(tq + kt * 16);
#pragma unroll
                for (int r = 0; r < 4; ++r)
                    S[qt][kt][r] = S[qt][kt][r] * scale + bv[r];
            }
        }
    }

    float inv[4];
#pragma unroll
    for (int qt = 0; qt < 4; ++qt) {
        float mx = -3e38f;
#pragma unroll
        for (int kt = 0; kt < 4; ++kt)
#pragma unroll
            for (int r = 0; r < 4; ++r) mx = fmaxf(mx, S[qt][kt][r]);
        mx = fmaxf(mx, __shfl_xor(mx, 16));
        mx = fmaxf(mx, __shfl_xor(mx, 32));
        float sm = 0.f;
#pragma unroll
        for (int kt = 0; kt < 4; ++kt)
#pragma unroll
            for (int r = 0; r < 4; ++r) {
                float e = __expf(S[qt][kt][r] - mx);
                S[qt][kt][r] = e;
                sm += e;
            }
        sm += __shfl_xor(sm, 16);
        sm += __shfl_xor(sm, 32);
        inv[qt] = 1.f / sm;
    }

    unsigned int w_[4][4][2];
#pragma unroll
    for (int qt = 0; qt < 4; ++qt)
#pragma unroll
        for (int t = 0; t < 4; ++t) {
            w_[qt][t][0] = pk2(S[qt][t][0], S[qt][t][1]);
            w_[qt][t][1] = pk2(S[qt][t][2], S[qt][t][3]);
        }

    int srcA = la + (((2 * lb)     & 3) << 4);
    int srcB = la + (((2 * lb + 1) & 3) << 4);
    bool hiT = (lb >> 1) & 1;

    f32x4 O[2][4];
#pragma unroll
    for (int dt = 0; dt < 2; ++dt)
#pragma unroll
        for (int qt = 0; qt < 4; ++qt) O[dt][qt] = (f32x4){0.f, 0.f, 0.f, 0.f};

#pragma unroll
    for (int kk = 0; kk < 2; ++kk) {
        bf16x8 vf[2];
#pragma unroll
        for (int dt = 0; dt < 2; ++dt)
            vf[dt] = *reinterpret_cast<const bf16x8*>(
                vtb + (h * 32 + dt * 16 + la) * 56 + kk * 32 + lb * 8);
        int tl = kk * 2;
#pragma unroll
        for (int qt = 0; qt < 4; ++qt) {
            unsigned int a0 = __shfl(w_[qt][tl][0],     srcA);
            unsigned int b0 = __shfl(w_[qt][tl + 1][0], srcA);
            unsigned int a1 = __shfl(w_[qt][tl][1],     srcA);
            unsigned int b1 = __shfl(w_[qt][tl + 1][1], srcA);
            unsigned int a2 = __shfl(w_[qt][tl][0],     srcB);
            unsigned int b2 = __shfl(w_[qt][tl + 1][0], srcB);
            unsigned int a3 = __shfl(w_[qt][tl][1],     srcB);
            unsigned int b3 = __shfl(w_[qt][tl + 1][1], srcB);
            u32x4 uu = { hiT ? b0 : a0, hiT ? b1 : a1, hiT ? b2 : a2, hiT ? b3 : a3 };
            bf16x8 pf = __builtin_bit_cast(bf16x8, uu);
#pragma unroll
            for (int dt = 0; dt < 2; ++dt)
                O[dt][qt] = __builtin_amdgcn_mfma_f32_16x16x32_bf16(vf[dt], pf, O[dt][qt], 0, 0, 0);
        }
    }

    // ---- normalized O -> attw (aliases xn; xn dead since phase-2 barrier) ----
    __bf16 (*attw)[152] = (__bf16(*)[152])xnb;
#pragma unroll
    for (int qt = 0; qt < 4; ++qt) {
        int q = qt * 16 + la;
        if (q < 49) {
            float iv = inv[qt];
#pragma unroll
            for (int dt = 0; dt < 2; ++dt) {
                unsigned int s0 = pk2(O[dt][qt][0] * iv, O[dt][qt][1] * iv);
                unsigned int s1 = pk2(O[dt][qt][2] * iv, O[dt][qt][3] * iv);
                uint2 st = {s0, s1};
                *reinterpret_cast<uint2*>(&attw[q][h * 32 + dt * 16 + lb * 4]) = st;
            }
        }
    }
    __syncthreads();

    // ---- phase 4: proj, wave h computes C[q=0..63][n=h*32..h*32+31] ----
    int n0 = h * 32;
    f32x4 pacc[4][2];
#pragma unroll
    for (int nt = 0; nt < 2; ++nt) {
        float bv = projb[n0 + nt * 16 + la];
#pragma unroll
        for (int s = 0; s < 4; ++s) pacc[s][nt] = (f32x4){bv, bv, bv, bv};
    }
#pragma unroll
    for (int kt = 0; kt < 4; ++kt) {
        bf16x8 ar[4];
#pragma unroll
        for (int s = 0; s < 4; ++s)
            ar[s] = *reinterpret_cast<const bf16x8*>(&attw[s * 16 + la][kt * 32 + lb * 8]);
#pragma unroll
        for (int nt = 0; nt < 2; ++nt) {
            bf16x8 br = *reinterpret_cast<const bf16x8*>(
                projwt + (long)(n0 + nt * 16 + la) * 128 + kt * 32 + lb * 8);
#pragma unroll
            for (int s = 0; s < 4; ++s)
                pacc[s][nt] = __builtin_amdgcn_mfma_f32_16x16x32_bf16(
                    ar[s], br, pacc[s][nt], 0, 0, 0);
        }
    }

    // ---- epilogue: window-reverse + unshift + x residual -> bf16 y ----
#pragma unroll
    for (int s = 0; s < 4; ++s) {
#pragma unroll
        for (int r = 0; r < 4; ++r) {
            int q = s * 16 + lb * 4 + r;
            if (q < 49) {
                long to = win_to_tok(win * 49 + q);
#pragma unroll
                for (int nt = 0; nt < 2; ++nt) {
                    int col = n0 + nt * 16 + la;
                    y[to * C_ + col] =
                        __float2bfloat16(pacc[s][nt][r] + x[to * C_ + col]);
                }
            }
        }
    }
}

// ---------------------------------------------------------------------------
// Fused MLP v8 (R15 version, verbatim — proven): bf16 y, 512-thread blocks,
// single 32 KB LDS weight buffer, XOR-swizzled rows. out (f32) written once.
// ---------------------------------------------------------------------------
__global__ __launch_bounds__(512, 4) void mlp_fused(const bf16_t* __restrict__ y,
                                                    const float* __restrict__ g,
                                                    const float* __restrict__ b,
                                                    const bf16_t* __restrict__ w1t,
                                                    const float* __restrict__ b1,
                                                    const bf16_t* __restrict__ w2t,
                                                    const float* __restrict__ b2,
                                                    float* __restrict__ out)
{
    __shared__ uint4 ldsq[2048];             // 32 KB: [W1c 16KB | W2c 16KB]
    int tid  = threadIdx.x;
    int lane = tid & 63;
    int la = lane & 15, lb = lane >> 4;
    int m0 = (blockIdx.x * 8 + (tid >> 6)) * 32;

    auto stage = [&](int c) {
        char* d1 = (char*)&ldsq[0];
        const char* s1 = (const char*)w1t + (size_t)c * 16384;
#pragma unroll
        for (int i = 0; i < 2; ++i) {
            int idx = i * 512 + tid;             // 0..1023, 16B units
            int row = idx >> 4, colb = (idx & 15) * 16;
            uint4 v = *reinterpret_cast<const uint4*>(s1 + idx * 16);
            *reinterpret_cast<uint4*>(d1 + row * 256 + (colb ^ ((row & 7) << 4))) = v;
        }
        char* d2 = (char*)&ldsq[1024];
        const char* s2 = (const char*)w2t + (size_t)c * 128;
#pragma unroll
        for (int i = 0; i < 2; ++i) {
            int idx = i * 512 + tid;             // 0..1023
            int row = idx >> 3, colb = (idx & 7) * 16;
            uint4 v = *reinterpret_cast<const uint4*>(s2 + (size_t)row * 1024 + colb);
            *reinterpret_cast<uint4*>(d2 + row * 128 + (colb ^ ((row & 7) << 4))) = v;
        }
    };

    // ---- LN2 -> fragments for 2 row-subtiles ----
    bf16x8 af[2][4];
#pragma unroll
    for (int s = 0; s < 2; ++s) {
        const bf16_t* yr = y + (long)(m0 + s * 16 + la) * C_;
        float vals[4][8];
        float sm = 0.f, qs = 0.f;
#pragma unroll
        for (int kt = 0; kt < 4; ++kt) {
            bf16x8 v8 = *reinterpret_cast<const bf16x8*>(yr + kt * 32 + lb * 8);
#pragma unroll
            for (int j = 0; j < 8; ++j) {
                float v = (float)v8[j];
                vals[kt][j] = v; sm += v; qs += v * v;
            }
        }
        sm += __shfl_xor(sm, 16); sm += __shfl_xor(sm, 32);
        qs += __shfl_xor(qs, 16); qs += __shfl_xor(qs, 32);
        float mean = sm * (1.f / 128.f);
        float rstd = rsqrtf(qs * (1.f / 128.f) - mean * mean + 1e-5f);
#pragma unroll
        for (int kt = 0; kt < 4; ++kt)
#pragma unroll
            for (int j = 0; j < 8; ++j) {
                int col = kt * 32 + lb * 8 + j;
                af[s][kt][j] = (__bf16)((vals[kt][j] - mean) * rstd * g[col] + b[col]);
            }
    }

    f32x4 acc[2][8];
#pragma unroll
    for (int nt2 = 0; nt2 < 8; ++nt2) {
        f32x4 bv = *reinterpret_cast<const f32x4*>(b2 + nt2 * 16 + lb * 4);
#pragma unroll
        for (int s = 0; s < 2; ++s) acc[s][nt2] = bv;
    }

    int srcA = la + (((2 * lb)     & 3) << 4);
    int srcB = la + (((2 * lb + 1) & 3) << 4);
    bool hiT = (lb >> 1) & 1;

    for (int c = 0; c < 8; ++c) {
        stage(c);
        __syncthreads();

        const char* L1 = (const char*)&ldsq[0];
        const char* L2 = (const char*)&ldsq[1024];

        f32x4 hacc[2][4];
#pragma unroll
        for (int nt = 0; nt < 4; ++nt) {
            f32x4 bv = *reinterpret_cast<const f32x4*>(b1 + c * 64 + nt * 16 + lb * 4);
#pragma unroll
            for (int s = 0; s < 2; ++s) hacc[s][nt] = bv;
        }
#pragma unroll
        for (int kt = 0; kt < 4; ++kt)
#pragma unroll
            for (int nt = 0; nt < 4; ++nt) {
                int row = nt * 16 + la;
                bf16x8 w1f = *reinterpret_cast<const bf16x8*>(
                    L1 + row * 256 + ((kt * 64 + lb * 16) ^ ((row & 7) << 4)));
#pragma unroll
                for (int s = 0; s < 2; ++s)
                    hacc[s][nt] = __builtin_amdgcn_mfma_f32_16x16x32_bf16(
                        w1f, af[s][kt], hacc[s][nt], 0, 0, 0);
            }
        unsigned int wpk[2][4][2];
#pragma unroll
        for (int s = 0; s < 2; ++s)
#pragma unroll
            for (int t = 0; t < 4; ++t) {
                f32x4 hv = hacc[s][t];
#pragma unroll
                for (int r = 0; r < 4; ++r) hv[r] = gelu_f(hv[r]);
                wpk[s][t][0] = pk2(hv[0], hv[1]);
                wpk[s][t][1] = pk2(hv[2], hv[3]);
            }
#pragma unroll
        for (int kk = 0; kk < 2; ++kk) {
            int tl = kk * 2;
#pragma unroll
            for (int s = 0; s < 2; ++s) {
                unsigned int a0 = __shfl(wpk[s][tl][0],     srcA);
                unsigned int b0 = __shfl(wpk[s][tl + 1][0], srcA);
                unsigned int a1 = __shfl(wpk[s][tl][1],     srcA);
                unsigned int b1v = __shfl(wpk[s][tl + 1][1], srcA);
                unsigned int a2 = __shfl(wpk[s][tl][0],     srcB);
                unsigned int b2v = __shfl(wpk[s][tl + 1][0], srcB);
                unsigned int a3 = __shfl(wpk[s][tl][1],     srcB);
                unsigned int b3v = __shfl(wpk[s][tl + 1][1], srcB);
                u32x4 uu = { hiT ? b0 : a0, hiT ? b1v : a1, hiT ? b2v : a2, hiT ? b3v : a3 };
                bf16x8 pf = __builtin_bit_cast(bf16x8, uu);
#pragma unroll
                for (int nt2 = 0; nt2 < 8; ++nt2) {
                    int row2 = nt2 * 16 + la;
                    bf16x8 w2f = *reinterpret_cast<const bf16x8*>(
                        L2 + row2 * 128 + ((kk * 64 + lb * 16) ^ ((row2 & 7) << 4)));
                    acc[s][nt2] = __builtin_amdgcn_mfma_f32_16x16x32_bf16(
                        w2f, pf, acc[s][nt2], 0, 0, 0);
                }
            }
        }
        __syncthreads();
    }

    // ---- epilogue: + y residual (bf16) -> f32 out ----
#pragma unroll
    for (int s = 0; s < 2; ++s) {
        long m = m0 + s * 16 + la;
        const bf16_t* yrow = y + m * C_;
        float* orow = out + m * C_;
#pragma unroll
        for (int nt2 = 0; nt2 < 8; ++nt2) {
            int n2 = nt2 * 16 + lb * 4;
            bf16x4 rb = *reinterpret_cast<const bf16x4*>(yrow + n2);
            f32x4 val = acc[s][nt2];
#pragma unroll
            for (int r = 0; r < 4; ++r) val[r] += (float)rb[r];
            *reinterpret_cast<f32x4*>(orow + n2) = val;
        }
    }
}

// ---------------------------------------------------------------------------
extern "C" void kernel_launch(void* const* d_in, const int* in_sizes, int n_in,
                              void* d_out, int out_size, void* d_ws, size_t ws_size,
                              hipStream_t stream)
{
    (void)in_sizes; (void)n_in; (void)out_size;

    const float* x      = (const float*)d_in[0];
    const float* n1g    = (const float*)d_in[1];
    const float* n1b    = (const float*)d_in[2];
    const float* qkv_w  = (const float*)d_in[3];
    const float* qkv_b  = (const float*)d_in[4];
    const float* proj_w = (const float*)d_in[5];
    const float* proj_b = (const float*)d_in[6];
    const float* rpb    = (const float*)d_in[7];
    const float* n2g    = (const float*)d_in[8];
    const float* n2b    = (const float*)d_in[9];
    const float* fc1_w  = (const float*)d_in[10];
    const float* fc1_b  = (const float*)d_in[11];
    const float* fc2_w  = (const float*)d_in[12];
    const float* fc2_b  = (const float*)d_in[13];

    char* ws = (char*)d_ws;

    const size_t yb_sz  = (size_t)M_ * 128 * 2;              // 51,380,224 (bf16 y)
    const size_t w_sz   = (size_t)(128 * 384 + 128 * 128 + 128 * 512 + 512 * 128) * 2;
    const size_t tb_sz  = (size_t)4 * 4 * 49 * 64 * 4;       // 200,704 (bias tbl)
    const size_t need   = yb_sz + w_sz + tb_sz;              // ~51.9 MB

    if (need > ws_size) {
        sentinel_kernel<<<1, 256, 0, stream>>>((float*)d_out);
        return;
    }

    bf16_t* yb      = (bf16_t*)ws;
    bf16_t* qkv_wt  = (bf16_t*)(ws + yb_sz);
    bf16_t* proj_wt = qkv_wt + 128 * 384;
    bf16_t* fc1_wt  = proj_wt + 128 * 128;
    bf16_t* fc2_wt  = fc1_wt + 128 * 512;
    float*  btbl    = (float*)(ws + yb_sz + w_sz);

    transpose_w<<<(128 * 384 + 255) / 256, 256, 0, stream>>>(qkv_w, qkv_wt, 128, 384);
    transpose_w<<<(128 * 128 + 255) / 256, 256, 0, stream>>>(proj_w, proj_wt, 128, 128);
    transpose_w<<<(128 * 512 + 255) / 256, 256, 0, stream>>>(fc1_w, fc1_wt, 128, 512);
    transpose_w<<<(512 * 128 + 255) / 256, 256, 0, stream>>>(fc2_w, fc2_wt, 512, 128);
    build_bias_tbl<<<(4 * 4 * 49 * 64 + 255) / 256, 256, 0, stream>>>(rpb, btbl);

    // LN1 + qkv + attention + proj + window-reverse + residual -> bf16 y
    swin_fused<<<NWIN, 256, 0, stream>>>(x, n1g, n1b, qkv_wt, qkv_b, btbl,
                                         proj_wt, proj_b, yb);
    // LN2 + fc1 + GELU + fc2 + residual -> f32 d_out
    mlp_fused<<<M_ / 256, 512, 0, stream>>>(
        yb, n2g, n2b, fc1_wt, fc1_b, fc2_wt, fc2_b, (float*)d_out);
}